// Round 6
// baseline (24018.106 us; speedup 1.0000x reference)
//
#include <hip/hip_runtime.h>
#include <hip/hip_bf16.h>
#include <math.h>

#define TT 64
#define NN 8
#define BB 128
#define DD 128
#define HH 512
#define SS 64
#define KK 16
#define AA 16
#define NB 1024
#define H3 (3*HH)       /* 1536 */
#define KC 16           /* k-chunk of Wh streamed through LDS */
#define SCAN_SMEM ((8*HH + KC*H3)*4)   /* 16KB h + 96KB W = 114688 B */

__device__ __forceinline__ float sigm(float x){ return 1.0f/(1.0f+expf(-x)); }

// ---------------- done-layout detection + mask expansion ----------------
__global__ __launch_bounds__(256) void k_detect(const unsigned char* __restrict__ raw,
                                                int* __restrict__ flag)
{
  __shared__ int cA, cB;
  if (threadIdx.x == 0){ cA = 0; cB = 0; }
  __syncthreads();
  int a = 0, b = 0;
  for (int i = threadIdx.x; i < TT*NB; i += 256){
    unsigned char v = raw[i];
    if (v > 1) a++;
    if ((i & 3) != 0 && v != 0) b++;
  }
  atomicAdd(&cA, a); atomicAdd(&cB, b);
  __syncthreads();
  if (threadIdx.x == 0) *flag = (cB == 0) ? 0 : (cA == 0 ? 1 : 2);
}

__global__ __launch_bounds__(256) void k_mask(const unsigned char* __restrict__ raw,
                                              const int* __restrict__ flag,
                                              float* __restrict__ mask)
{
  int i = blockIdx.x*256 + threadIdx.x;
  if (i >= TT*NB) return;
  int f = *flag;
  int v;
  if (f == 1)      v = (int)raw[i];
  else if (f == 0) v = ((const int*)raw)[i];
  else             v = (((const float*)raw)[i] != 0.0f);
  mask[i] = v ? 0.f : 1.f;   // 0 => reset carry
}

// ---------------- small setup kernels ----------------

__global__ __launch_bounds__(256) void k_e(const float* __restrict__ W_e1, const float* __restrict__ b_e1,
                                           const float* __restrict__ W_e2, const float* __restrict__ b_e2,
                                           float* __restrict__ e_out)
{
  __shared__ float r1[KK*SS];
  int tid = threadIdx.x;
  for (int i=0;i<4;++i){ int l = tid + i*256; float v = W_e1[l] + b_e1[l & 63]; r1[l] = v > 0.f ? v : 0.f; }
  __syncthreads();
  for (int i=0;i<4;++i){
    int l = tid + i*256; int k = l >> 6, s = l & 63;
    float acc = b_e2[s];
    #pragma unroll 8
    for (int sp=0; sp<64; ++sp) acc += r1[k*64+sp] * W_e2[sp*64 + s];
    e_out[l] = tanhf(acc);
  }
}

__global__ __launch_bounds__(256) void k_w1b1(const float* __restrict__ e, const float* __restrict__ W_w1,
                                              const float* __restrict__ b_w1, const float* __restrict__ W_b1,
                                              const float* __restrict__ b_b1, float* __restrict__ w1,
                                              float* __restrict__ b1)
{
  __shared__ float es[KK*SS];
  int tid = threadIdx.x;
  for (int i=0;i<4;++i) es[tid + i*256] = e[tid + i*256];
  __syncthreads();
  for (int i=0;i<4;++i){
    int l = blockIdx.x*1024 + tid + i*256;
    int k = l >> 13, m = l & 8191;
    float acc = b_w1[m];
    #pragma unroll 8
    for (int s=0;s<64;++s) acc += es[k*64+s] * W_w1[(size_t)s*8192 + m];
    w1[l] = acc;
  }
  if (blockIdx.x == 0){
    int k = tid >> 4, a = tid & 15;
    float acc = b_b1[a];
    #pragma unroll 8
    for (int s=0;s<64;++s) acc += es[k*64+s] * W_b1[s*16 + a];
    b1[tid] = acc;
  }
}

__global__ __launch_bounds__(256) void k_se(const float* __restrict__ e, float* __restrict__ outse)
{
  __shared__ float4 es[256];
  es[threadIdx.x] = ((const float4*)e)[threadIdx.x];
  __syncthreads();
  const int total4 = TT*BB*KK*SS/4;
  for (int i = blockIdx.x*256 + threadIdx.x; i < total4; i += gridDim.x*256)
    ((float4*)outse)[i] = es[i & 255];
}

__global__ void k_copy(const float* __restrict__ src, float* __restrict__ dst, int n4)
{
  int i = blockIdx.x*blockDim.x + threadIdx.x;
  if (i < n4) ((float4*)dst)[i] = ((const float4*)src)[i];
}

// ---------------- generic tiled f32 GEMM: C = act(A@W + bias) ----------------
template<int RELU>
__global__ __launch_bounds__(256) void gemm_bias_act(
    const float* __restrict__ A, const float* __restrict__ W,
    const float* __restrict__ bias, float* __restrict__ C,
    int M, int Kd, int Nc)
{
  __shared__ float As[16][72];
  __shared__ float Bs[16][72];
  int tid = threadIdx.x;
  int tx = tid & 15, ty = tid >> 4;
  int rowBase = blockIdx.y * 64;
  int colBase = blockIdx.x * 64;
  float acc[4][4] = {};
  for (int k0 = 0; k0 < Kd; k0 += 16){
    {
      int r  = tid >> 2;
      int kb = (tid & 3) * 4;
      float4 v = *(const float4*)&A[(size_t)(rowBase + r)*Kd + k0 + kb];
      As[kb+0][r]=v.x; As[kb+1][r]=v.y; As[kb+2][r]=v.z; As[kb+3][r]=v.w;
    }
    #pragma unroll
    for (int i=0;i<4;++i){
      int l = i*256 + tid;
      int kk = l >> 6, c = l & 63;
      Bs[kk][c] = W[(size_t)(k0+kk)*Nc + colBase + c];
    }
    __syncthreads();
    #pragma unroll
    for (int kk=0;kk<16;++kk){
      float4 a4 = *(const float4*)&As[kk][ty*4];
      float4 b4 = *(const float4*)&Bs[kk][tx*4];
      float av[4]={a4.x,a4.y,a4.z,a4.w}, bv[4]={b4.x,b4.y,b4.z,b4.w};
      #pragma unroll
      for (int i=0;i<4;++i)
        #pragma unroll
        for (int j=0;j<4;++j) acc[i][j] += av[i]*bv[j];
    }
    __syncthreads();
  }
  int c0 = colBase + tx*4;
  float4 bv4 = *(const float4*)&bias[c0];
  float bb[4]={bv4.x,bv4.y,bv4.z,bv4.w};
  for (int i=0;i<4;++i){
    int r = rowBase + ty*4 + i;
    float o[4];
    #pragma unroll
    for (int j=0;j<4;++j){ float v = acc[i][j] + bb[j]; if (RELU) v = v>0.f?v:0.f; o[j]=v; }
    *(float4*)&C[(size_t)r*Nc + c0] = make_float4(o[0],o[1],o[2],o[3]);
  }
}

// ---------------- sync-free persistent dual-GRU scan ----------------
// Rows-only split: the recurrence is row-independent, so each block owns 8 batch-rows
// for ALL 512 cols and runs ALL CH steps with no inter-block communication.
// Grid 256 x 512 thr: gru = bid&1 (XCD parity => one 3MB Wh per XCD L2), sub = bid>>1.
// h slice (8x512) resident in LDS for the whole launch; Wh streamed from L2 in 16-k
// chunks through LDS with register-prefetch double buffering. Thread = one h-column.
__global__ __launch_bounds__(512, 1) void gru_scan2(
    const float* __restrict__ h01, const float* __restrict__ h02,
    const float* __restrict__ gbuf1, const float* __restrict__ gbuf2,
    const float* __restrict__ Wh1, const float* __restrict__ Wh2,
    const float* __restrict__ bhn1, const float* __restrict__ bhn2,
    const float* __restrict__ mask, int t0, int CH,
    float* __restrict__ buf1, float* __restrict__ buf2,
    float* __restrict__ hl1, float* __restrict__ hl2)
{
  extern __shared__ float smem[];
  float* hsm = smem;               // [8][512]  16 KB (reads are wave-uniform broadcasts)
  float* Wsh = smem + 8*HH;        // [KC][1536] 96 KB

  int bid = blockIdx.x;
  int gru = bid & 1, sub = bid >> 1;      // sub in [0,128)
  int rowBase = sub << 3;                 // 8 rows per block
  int tid = threadIdx.x;                  // owns column c = tid

  const float* h0 = gru ? h02  : h01;
  const float* gb = gru ? gbuf2: gbuf1;
  const float* Wh = gru ? Wh2  : Wh1;
  float bhn_c     = (gru ? bhn2 : bhn1)[tid];
  float* buf      = gru ? buf2 : buf1;
  float* hl       = gru ? hl2  : hl1;

  // init resident h slice
  {
    int r = tid >> 6, cb = tid & 63;
    #pragma unroll
    for (int q=0;q<8;++q) hsm[r*HH + cb + q*64] = h0[(size_t)(rowBase+r)*HH + cb + q*64];
  }

  const int NCHK = HH / KC;   // 32 chunks per step
  for (int lt = 0; lt < CH; ++lt){
    __syncthreads();   // (A) prev epilogue hsm writes done
    // apply reset mask in place
    {
      int r = tid >> 6, cb = tid & 63;
      float m = mask[(size_t)(t0+lt)*NB + rowBase + r];
      #pragma unroll
      for (int q=0;q<8;++q) hsm[r*HH + cb + q*64] *= m;
    }
    // prefetch chunk 0 of Wh into registers
    float4 pf[12];
    {
      const float4* src = (const float4*)Wh;
      #pragma unroll
      for (int j=0;j<12;++j) pf[j] = src[tid + j*512];
    }

    float acc[8][3];
    #pragma unroll
    for (int r=0;r<8;++r){ acc[r][0]=0.f; acc[r][1]=0.f; acc[r][2]=0.f; }

    for (int ch = 0; ch < NCHK; ++ch){
      __syncthreads();   // (B) prev chunk's Wsh reads done / (ch==0) mask writes visible
      {
        float4* dst = (float4*)Wsh;
        #pragma unroll
        for (int j=0;j<12;++j) dst[tid + j*512] = pf[j];
      }
      __syncthreads();   // (C) Wsh visible
      if (ch + 1 < NCHK){
        const float4* src = (const float4*)&Wh[(size_t)(ch+1)*KC*H3];
        #pragma unroll
        for (int j=0;j<12;++j) pf[j] = src[tid + j*512];   // hides under compute below
      }
      int kb = ch * KC;
      #pragma unroll
      for (int k4 = 0; k4 < KC; k4 += 4){
        float w0[4], w1[4], w2[4];
        #pragma unroll
        for (int p=0;p<4;++p){
          int wb = (k4+p)*H3;
          w0[p] = Wsh[wb + tid];
          w1[p] = Wsh[wb + 512 + tid];
          w2[p] = Wsh[wb + 1024 + tid];
        }
        #pragma unroll
        for (int r=0;r<8;++r){
          float4 a = *(const float4*)&hsm[r*HH + kb + k4];   // broadcast read
          acc[r][0] += a.x*w0[0] + a.y*w0[1] + a.z*w0[2] + a.w*w0[3];
          acc[r][1] += a.x*w1[0] + a.y*w1[1] + a.z*w1[2] + a.w*w1[3];
          acc[r][2] += a.x*w2[0] + a.y*w2[1] + a.z*w2[2] + a.w*w2[3];
        }
      }
    }
    __syncthreads();   // (D) all hsm reads done before epilogue overwrites

    const float* gi = gb + (size_t)lt*NB*H3;
    float* yo = buf + (size_t)lt*NB*HH;
    bool last = (lt == CH-1);
    #pragma unroll
    for (int r=0;r<8;++r){
      int row = rowBase + r;
      size_t gbase = (size_t)row*H3 + tid;
      float g_r = __builtin_nontemporal_load(&gi[gbase]);
      float g_z = __builtin_nontemporal_load(&gi[gbase + HH]);
      float g_n = __builtin_nontemporal_load(&gi[gbase + 2*HH]);
      float rg = sigm(g_r + acc[r][0]);
      float zg = sigm(g_z + acc[r][1]);
      float ng = tanhf(g_n + rg*(acc[r][2] + bhn_c));
      float o  = (1.f - zg)*ng + zg*hsm[r*HH + tid];   // own column only: no race
      hsm[r*HH + tid] = o;
      yo[(size_t)row*HH + tid] = o;
      if (last) hl[(size_t)row*HH + tid] = o;
    }
  }
}

// ---------------- logits + first-max argmax (chunked: t = t0 + local) ----------------
__global__ __launch_bounds__(256) void k_logits(const float* __restrict__ ae2,
    const float* __restrict__ e, float* __restrict__ out_logits, int* __restrict__ argk, int t0)
{
  __shared__ float es[KK*SS];
  int tid = threadIdx.x;
  for (int i=0;i<4;++i) es[tid + i*256] = e[tid + i*256];
  __syncthreads();
  int g = blockIdx.x*256 + tid;
  int t = t0 + (g >> 10), j = g & 1023;
  const float* arow = &ae2[(size_t)g * SS];
  float a[SS];
  #pragma unroll
  for (int i=0;i<16;++i){ float4 v = ((const float4*)arow)[i]; a[4*i]=v.x; a[4*i+1]=v.y; a[4*i+2]=v.z; a[4*i+3]=v.w; }
  float lg[KK];
  float best = -INFINITY; int bk = 0;
  for (int k=0;k<KK;++k){
    float s2 = 0.f;
    #pragma unroll 8
    for (int s=0;s<SS;++s) s2 += a[s]*es[k*SS+s];
    lg[k] = s2;
    if (s2 > best){ best = s2; bk = k; }
  }
  int n = j >> 7, b = j & 127;
  size_t ob = ((size_t)((t*BB + b)*NN + n)) * KK;
  #pragma unroll
  for (int k4=0;k4<4;++k4)
    *(float4*)&out_logits[ob + k4*4] = make_float4(lg[k4*4],lg[k4*4+1],lg[k4*4+2],lg[k4*4+3]);
  argk[(t*BB + b)*NN + n] = bk;   // (b,n)-major: matches reference's prob/q index quirk
}

// ---------------- q selection (chunked) ----------------
__global__ __launch_bounds__(64) void k_qsel(const float* __restrict__ y2,
    const float* __restrict__ w1, const float* __restrict__ b1,
    const int* __restrict__ argk, float* __restrict__ outq)
{
  __shared__ float yr[HH];
  __shared__ float part[64];
  int bj = blockIdx.x;
  int tid = threadIdx.x;
  const float4* row4 = (const float4*)&y2[(size_t)bj*HH];
  ((float4*)yr)[tid]    = row4[tid];
  ((float4*)yr)[tid+64] = row4[tid+64];
  __syncthreads();
  int k = argk[bj];
  int a = tid & 15, q4 = tid >> 4;
  const float* wp = &w1[(size_t)k*HH*AA + a];
  float s = 0.f;
  int h0 = q4*128;
  #pragma unroll 8
  for (int h=h0; h<h0+128; ++h) s += yr[h]*wp[(size_t)h*AA];
  part[tid] = s;
  __syncthreads();
  if (q4 == 0){
    float v = part[a] + part[a+16] + part[a+32] + part[a+48] + b1[k*AA + a];
    outq[(size_t)bj*AA + a] = v;
  }
}

// ---------------- orchestration ----------------
extern "C" void kernel_launch(void* const* d_in, const int* in_sizes, int n_in,
                              void* d_out, int out_size, void* d_ws, size_t ws_size,
                              hipStream_t stream)
{
  (void)in_sizes; (void)n_in; (void)out_size;
  const float* h1     = (const float*)d_in[0];
  const float* h2     = (const float*)d_in[1];
  const float* obs    = (const float*)d_in[2];
  const unsigned char* done_raw = (const unsigned char*)d_in[3];
  const float* W_embed=(const float*)d_in[4];  const float* b_embed=(const float*)d_in[5];
  const float* Wi1    =(const float*)d_in[6];  const float* bi1    =(const float*)d_in[7];
  const float* Wh1    =(const float*)d_in[8];  const float* bhn1   =(const float*)d_in[9];
  const float* W_sub  =(const float*)d_in[10]; const float* b_sub  =(const float*)d_in[11];
  const float* W_e1   =(const float*)d_in[12]; const float* b_e1   =(const float*)d_in[13];
  const float* W_e2   =(const float*)d_in[14]; const float* b_e2   =(const float*)d_in[15];
  const float* W_pol  =(const float*)d_in[16]; const float* b_pol  =(const float*)d_in[17];
  const float* Wi2    =(const float*)d_in[18]; const float* bi2    =(const float*)d_in[19];
  const float* Wh2    =(const float*)d_in[20]; const float* bhn2   =(const float*)d_in[21];
  const float* W_w1   =(const float*)d_in[22]; const float* b_w1   =(const float*)d_in[23];
  const float* W_b1   =(const float*)d_in[24]; const float* b_b1   =(const float*)d_in[25];

  float* out    = (float*)d_out;
  float* outHT1 = out;
  float* outHT2 = out + (size_t)NB*HH;
  float* outQ   = out + 2ull*NB*HH;
  float* outLG  = outQ + (size_t)TT*NB*AA;
  float* outSE  = outLG + (size_t)TT*BB*NN*KK;

  // ---- adaptive chunk size from ws_size ----
  const size_t fixed_f = 2ull*NB*HH + (size_t)TT*NB + 1024
                       + (size_t)KK*HH*AA + 256 + (size_t)TT*NB + 64;
  const size_t per_t_f = (size_t)NB*(2*HH + 2*H3 + SS);
  int CH = 64;
  while (CH > 1 && (fixed_f + per_t_f*(size_t)CH)*4 > ws_size) CH >>= 1;

  float* buf1   = (float*)d_ws;                        // y1 chunk: CH*NB*HH
  float* buf2   = buf1   + (size_t)CH*NB*HH;           // y2 chunk
  float* gbuf1  = buf2   + (size_t)CH*NB*HH;           // gi1 chunk: CH*NB*H3
  float* gbuf2  = gbuf1  + (size_t)CH*NB*H3;           // gi2 chunk
  float* ae2buf = gbuf2  + (size_t)CH*NB*H3;           // CH*NB*SS
  float* h_last1= ae2buf + (size_t)CH*NB*SS;
  float* h_last2= h_last1+ (size_t)NB*HH;
  float* maskp  = h_last2+ (size_t)NB*HH;
  float* ws_e   = maskp  + (size_t)TT*NB;
  float* ws_w1  = ws_e   + 1024;
  float* ws_b1  = ws_w1  + (size_t)KK*HH*AA;
  int*   ws_argk= (int*)(ws_b1 + 256);
  int*   ws_flag= (int*)(ws_argk + (size_t)TT*NB);

  hipFuncSetAttribute((const void*)gru_scan2,
                      hipFuncAttributeMaxDynamicSharedMemorySize, SCAN_SMEM);

  // phase 0
  k_detect<<<1,256,0,stream>>>(done_raw, ws_flag);
  k_mask<<<TT*NB/256,256,0,stream>>>(done_raw, ws_flag, maskp);
  k_e<<<1,256,0,stream>>>(W_e1,b_e1,W_e2,b_e2,ws_e);
  k_w1b1<<<128,256,0,stream>>>(ws_e,W_w1,b_w1,W_b1,b_b1,ws_w1,ws_b1);
  k_se<<<2048,256,0,stream>>>(ws_e,outSE);

  dim3 thr(256);
  const int NCH = TT / CH;
  for (int c = 0; c < NCH; ++c){
    int t0 = c * CH;
    const float* obs_c = obs + (size_t)t0*NB*DD;
    gemm_bias_act<1><<<dim3(HH/64, CH*NB/64),thr,0,stream>>>(obs_c, W_embed, b_embed, buf1, CH*NB, DD, HH);
    gemm_bias_act<0><<<dim3(H3/64, CH*NB/64),thr,0,stream>>>(buf1, Wi1, bi1, gbuf1, CH*NB, HH, H3);
    gemm_bias_act<1><<<dim3(HH/64, CH*NB/64),thr,0,stream>>>(obs_c, W_pol, b_pol, buf2, CH*NB, DD, HH);
    gemm_bias_act<0><<<dim3(H3/64, CH*NB/64),thr,0,stream>>>(buf2, Wi2, bi2, gbuf2, CH*NB, HH, H3);
    // whole-chunk dual-GRU scan: ONE regular launch, sync-free across blocks
    {
      const float* hi1 = (c == 0) ? h1 : h_last1;
      const float* hi2 = (c == 0) ? h2 : h_last2;
      gru_scan2<<<256, 512, SCAN_SMEM, stream>>>(hi1, hi2, gbuf1, gbuf2, Wh1, Wh2,
                                                 bhn1, bhn2, maskp, t0, CH,
                                                 buf1, buf2, h_last1, h_last2);
    }
    gemm_bias_act<0><<<dim3(SS/64, CH*NB/64),thr,0,stream>>>(buf1, W_sub, b_sub, ae2buf, CH*NB, HH, SS);
    k_logits<<<CH*NB/256,256,0,stream>>>(ae2buf, ws_e, outLG, ws_argk, t0);
    k_qsel<<<CH*NB,64,0,stream>>>(buf2, ws_w1, ws_b1, ws_argk + (size_t)t0*NB, outQ + (size_t)t0*NB*AA);
  }
  k_copy<<<512,256,0,stream>>>(h_last1, outHT1, NB*HH/4);
  k_copy<<<512,256,0,stream>>>(h_last2, outHT2, NB*HH/4);
}

// Round 7
// 8030.215 us; speedup vs baseline: 2.9910x; 2.9910x over previous
//
#include <hip/hip_runtime.h>
#include <hip/hip_bf16.h>
#include <math.h>

#define TT 64
#define NN 8
#define BB 128
#define DD 128
#define HH 512
#define SS 64
#define KK 16
#define AA 16
#define NB 1024
#define H3 (3*HH)       /* 1536 */

typedef float f4v __attribute__((ext_vector_type(4)));

__device__ __forceinline__ float sigm(float x){ return 1.0f/(1.0f+expf(-x)); }

// ---------------- done-layout detection + mask expansion ----------------
__global__ __launch_bounds__(256) void k_detect(const unsigned char* __restrict__ raw,
                                                int* __restrict__ flag)
{
  __shared__ int cA, cB;
  if (threadIdx.x == 0){ cA = 0; cB = 0; }
  __syncthreads();
  int a = 0, b = 0;
  for (int i = threadIdx.x; i < TT*NB; i += 256){
    unsigned char v = raw[i];
    if (v > 1) a++;
    if ((i & 3) != 0 && v != 0) b++;
  }
  atomicAdd(&cA, a); atomicAdd(&cB, b);
  __syncthreads();
  if (threadIdx.x == 0) *flag = (cB == 0) ? 0 : (cA == 0 ? 1 : 2);
}

__global__ __launch_bounds__(256) void k_mask(const unsigned char* __restrict__ raw,
                                              const int* __restrict__ flag,
                                              float* __restrict__ mask)
{
  int i = blockIdx.x*256 + threadIdx.x;
  if (i >= TT*NB) return;
  int f = *flag;
  int v;
  if (f == 1)      v = (int)raw[i];
  else if (f == 0) v = ((const int*)raw)[i];
  else             v = (((const float*)raw)[i] != 0.0f);
  mask[i] = v ? 0.f : 1.f;   // 0 => reset carry
}

// ---------------- small setup kernels ----------------

__global__ __launch_bounds__(256) void k_e(const float* __restrict__ W_e1, const float* __restrict__ b_e1,
                                           const float* __restrict__ W_e2, const float* __restrict__ b_e2,
                                           float* __restrict__ e_out)
{
  __shared__ float r1[KK*SS];
  int tid = threadIdx.x;
  for (int i=0;i<4;++i){ int l = tid + i*256; float v = W_e1[l] + b_e1[l & 63]; r1[l] = v > 0.f ? v : 0.f; }
  __syncthreads();
  for (int i=0;i<4;++i){
    int l = tid + i*256; int k = l >> 6, s = l & 63;
    float acc = b_e2[s];
    #pragma unroll 8
    for (int sp=0; sp<64; ++sp) acc += r1[k*64+sp] * W_e2[sp*64 + s];
    e_out[l] = tanhf(acc);
  }
}

__global__ __launch_bounds__(256) void k_w1b1(const float* __restrict__ e, const float* __restrict__ W_w1,
                                              const float* __restrict__ b_w1, const float* __restrict__ W_b1,
                                              const float* __restrict__ b_b1, float* __restrict__ w1,
                                              float* __restrict__ b1)
{
  __shared__ float es[KK*SS];
  int tid = threadIdx.x;
  for (int i=0;i<4;++i) es[tid + i*256] = e[tid + i*256];
  __syncthreads();
  for (int i=0;i<4;++i){
    int l = blockIdx.x*1024 + tid + i*256;
    int k = l >> 13, m = l & 8191;
    float acc = b_w1[m];
    #pragma unroll 8
    for (int s=0;s<64;++s) acc += es[k*64+s] * W_w1[(size_t)s*8192 + m];
    w1[l] = acc;
  }
  if (blockIdx.x == 0){
    int k = tid >> 4, a = tid & 15;
    float acc = b_b1[a];
    #pragma unroll 8
    for (int s=0;s<64;++s) acc += es[k*64+s] * W_b1[s*16 + a];
    b1[tid] = acc;
  }
}

__global__ __launch_bounds__(256) void k_se(const float* __restrict__ e, float* __restrict__ outse)
{
  __shared__ float4 es[256];
  es[threadIdx.x] = ((const float4*)e)[threadIdx.x];
  __syncthreads();
  const int total4 = TT*BB*KK*SS/4;
  for (int i = blockIdx.x*256 + threadIdx.x; i < total4; i += gridDim.x*256)
    ((float4*)outse)[i] = es[i & 255];
}

__global__ void k_copy(const float* __restrict__ src, float* __restrict__ dst, int n4)
{
  int i = blockIdx.x*blockDim.x + threadIdx.x;
  if (i < n4) ((float4*)dst)[i] = ((const float4*)src)[i];
}

// ---------------- generic tiled f32 GEMM: C = act(A@W + bias) ----------------
template<int RELU>
__global__ __launch_bounds__(256) void gemm_bias_act(
    const float* __restrict__ A, const float* __restrict__ W,
    const float* __restrict__ bias, float* __restrict__ C,
    int M, int Kd, int Nc)
{
  __shared__ float As[16][72];
  __shared__ float Bs[16][72];
  int tid = threadIdx.x;
  int tx = tid & 15, ty = tid >> 4;
  int rowBase = blockIdx.y * 64;
  int colBase = blockIdx.x * 64;
  float acc[4][4] = {};
  for (int k0 = 0; k0 < Kd; k0 += 16){
    {
      int r  = tid >> 2;
      int kb = (tid & 3) * 4;
      float4 v = *(const float4*)&A[(size_t)(rowBase + r)*Kd + k0 + kb];
      As[kb+0][r]=v.x; As[kb+1][r]=v.y; As[kb+2][r]=v.z; As[kb+3][r]=v.w;
    }
    #pragma unroll
    for (int i=0;i<4;++i){
      int l = i*256 + tid;
      int kk = l >> 6, c = l & 63;
      Bs[kk][c] = W[(size_t)(k0+kk)*Nc + colBase + c];
    }
    __syncthreads();
    #pragma unroll
    for (int kk=0;kk<16;++kk){
      float4 a4 = *(const float4*)&As[kk][ty*4];
      float4 b4 = *(const float4*)&Bs[kk][tx*4];
      float av[4]={a4.x,a4.y,a4.z,a4.w}, bv[4]={b4.x,b4.y,b4.z,b4.w};
      #pragma unroll
      for (int i=0;i<4;++i)
        #pragma unroll
        for (int j=0;j<4;++j) acc[i][j] += av[i]*bv[j];
    }
    __syncthreads();
  }
  int c0 = colBase + tx*4;
  float4 bv4 = *(const float4*)&bias[c0];
  float bb[4]={bv4.x,bv4.y,bv4.z,bv4.w};
  for (int i=0;i<4;++i){
    int r = rowBase + ty*4 + i;
    float o[4];
    #pragma unroll
    for (int j=0;j<4;++j){ float v = acc[i][j] + bb[j]; if (RELU) v = v>0.f?v:0.f; o[j]=v; }
    *(float4*)&C[(size_t)r*Nc + c0] = make_float4(o[0],o[1],o[2],o[3]);
  }
}

// ---------------- per-step dual-GRU 3-gate GEMM with fused gate math ----------------
// grid 512 x 256 thr: gru = bid&1, ct = (bid>>1)&7 (64 H-cols), rt = bid>>4 (32 rows).
// Per thread (tx=tid&15, ty=tid>>4): 2 rows x 4 cols x 3 gates = 24 accs.
// h-tile staged MASKED in LDS (also provides hval); Wh 3-gate slice staged per 16-k chunk.
__global__ __launch_bounds__(256) void gru_gemm_step(
    const float* __restrict__ hp1, const float* __restrict__ hp2,
    const float* __restrict__ gi1, const float* __restrict__ gi2,
    const float* __restrict__ Wh1, const float* __restrict__ Wh2,
    const float* __restrict__ bhn1, const float* __restrict__ bhn2,
    const float* __restrict__ mask_t,
    float* __restrict__ ho1, float* __restrict__ ho2)
{
  __shared__ float As[16][40];      // [kk][row 0..31] masked h-tile
  __shared__ float Bs[16][3][68];   // [kk][gate][col 0..63]
  __shared__ float dms[32];

  int bid = blockIdx.x;
  int gru = bid & 1;
  int ct  = (bid >> 1) & 7;
  int rt  = bid >> 4;                 // 0..31
  int rowBase = rt << 5;              // 32 rows
  int colBase = ct << 6;              // 64 cols
  int tid = threadIdx.x, tx = tid & 15, ty = tid >> 4;

  const float* hp   = gru ? hp2  : hp1;
  const float* gi   = gru ? gi2  : gi1;
  const float* Wh   = gru ? Wh2  : Wh1;
  const float* bhnp = gru ? bhn2 : bhn1;
  float*       ho   = gru ? ho2  : ho1;

  if (tid < 32) dms[tid] = mask_t[rowBase + tid];
  __syncthreads();

  float acc[3][2][4] = {};
  float hval[2][4];

  for (int k0 = 0; k0 < HH; k0 += 16){
    // stage A (masked): 32 rows x 16 k; thread: r = tid>>3, kb = (tid&7)*2
    {
      int r = tid >> 3, kb = (tid & 7) * 2;
      float m = dms[r];
      float2 v = *(const float2*)&hp[(size_t)(rowBase + r)*HH + k0 + kb];
      As[kb+0][r] = v.x * m;
      As[kb+1][r] = v.y * m;
    }
    // stage B: 16k x 3g x 64c = 3072 floats, 12/thread, 256B-coalesced per (kk,g)
    #pragma unroll
    for (int i=0;i<12;++i){
      int l = i*256 + tid;
      int c = l & 63, t = l >> 6;      // t = kk*3+g
      int g = t % 3, kk = t / 3;
      Bs[kk][g][c] = Wh[(size_t)(k0+kk)*H3 + g*HH + colBase + c];
    }
    __syncthreads();
    if (k0 - colBase == ((tx >> 2) << 4)){   // own columns live in this k-chunk (masked)
      #pragma unroll
      for (int i=0;i<2;++i)
        #pragma unroll
        for (int j=0;j<4;++j)
          hval[i][j] = As[(tx & 3)*4 + j][ty*2 + i];
    }
    #pragma unroll
    for (int kk=0;kk<16;++kk){
      float2 a2 = *(const float2*)&As[kk][ty*2];
      float4 b0 = *(const float4*)&Bs[kk][0][tx*4];
      float4 b1 = *(const float4*)&Bs[kk][1][tx*4];
      float4 b2 = *(const float4*)&Bs[kk][2][tx*4];
      float av[2] = {a2.x, a2.y};
      float b0v[4]={b0.x,b0.y,b0.z,b0.w};
      float b1v[4]={b1.x,b1.y,b1.z,b1.w};
      float b2v[4]={b2.x,b2.y,b2.z,b2.w};
      #pragma unroll
      for (int i=0;i<2;++i)
        #pragma unroll
        for (int j=0;j<4;++j){
          acc[0][i][j] += av[i]*b0v[j];
          acc[1][i][j] += av[i]*b1v[j];
          acc[2][i][j] += av[i]*b2v[j];
        }
    }
    __syncthreads();
  }

  int c0 = colBase + tx*4;
  float4 bn4 = *(const float4*)&bhnp[c0];
  float bnv[4] = {bn4.x, bn4.y, bn4.z, bn4.w};
  #pragma unroll
  for (int i=0;i<2;++i){
    int row = rowBase + ty*2 + i;
    size_t gb = (size_t)row*H3 + c0;
    f4v g_r = __builtin_nontemporal_load((const f4v*)&gi[gb]);
    f4v g_z = __builtin_nontemporal_load((const f4v*)&gi[gb + HH]);
    f4v g_n = __builtin_nontemporal_load((const f4v*)&gi[gb + 2*HH]);
    float o[4];
    #pragma unroll
    for (int j=0;j<4;++j){
      float rg = sigm(g_r[j] + acc[0][i][j]);
      float zg = sigm(g_z[j] + acc[1][i][j]);
      float ng = tanhf(g_n[j] + rg*(acc[2][i][j] + bnv[j]));
      o[j] = (1.f - zg)*ng + zg*hval[i][j];
    }
    *(float4*)&ho[(size_t)row*HH + c0] = make_float4(o[0],o[1],o[2],o[3]);
  }
}

// ---------------- logits + first-max argmax (chunked: t = t0 + local) ----------------
__global__ __launch_bounds__(256) void k_logits(const float* __restrict__ ae2,
    const float* __restrict__ e, float* __restrict__ out_logits, int* __restrict__ argk, int t0)
{
  __shared__ float es[KK*SS];
  int tid = threadIdx.x;
  for (int i=0;i<4;++i) es[tid + i*256] = e[tid + i*256];
  __syncthreads();
  int g = blockIdx.x*256 + tid;
  int t = t0 + (g >> 10), j = g & 1023;
  const float* arow = &ae2[(size_t)g * SS];
  float a[SS];
  #pragma unroll
  for (int i=0;i<16;++i){ float4 v = ((const float4*)arow)[i]; a[4*i]=v.x; a[4*i+1]=v.y; a[4*i+2]=v.z; a[4*i+3]=v.w; }
  float lg[KK];
  float best = -INFINITY; int bk = 0;
  for (int k=0;k<KK;++k){
    float s2 = 0.f;
    #pragma unroll 8
    for (int s=0;s<SS;++s) s2 += a[s]*es[k*SS+s];
    lg[k] = s2;
    if (s2 > best){ best = s2; bk = k; }
  }
  int n = j >> 7, b = j & 127;
  size_t ob = ((size_t)((t*BB + b)*NN + n)) * KK;
  #pragma unroll
  for (int k4=0;k4<4;++k4)
    *(float4*)&out_logits[ob + k4*4] = make_float4(lg[k4*4],lg[k4*4+1],lg[k4*4+2],lg[k4*4+3]);
  argk[(t*BB + b)*NN + n] = bk;   // (b,n)-major: matches reference's prob/q index quirk
}

// ---------------- q selection (chunked) ----------------
__global__ __launch_bounds__(64) void k_qsel(const float* __restrict__ y2,
    const float* __restrict__ w1, const float* __restrict__ b1,
    const int* __restrict__ argk, float* __restrict__ outq)
{
  __shared__ float yr[HH];
  __shared__ float part[64];
  int bj = blockIdx.x;
  int tid = threadIdx.x;
  const float4* row4 = (const float4*)&y2[(size_t)bj*HH];
  ((float4*)yr)[tid]    = row4[tid];
  ((float4*)yr)[tid+64] = row4[tid+64];
  __syncthreads();
  int k = argk[bj];
  int a = tid & 15, q4 = tid >> 4;
  const float* wp = &w1[(size_t)k*HH*AA + a];
  float s = 0.f;
  int h0 = q4*128;
  #pragma unroll 8
  for (int h=h0; h<h0+128; ++h) s += yr[h]*wp[(size_t)h*AA];
  part[tid] = s;
  __syncthreads();
  if (q4 == 0){
    float v = part[a] + part[a+16] + part[a+32] + part[a+48] + b1[k*AA + a];
    outq[(size_t)bj*AA + a] = v;
  }
}

// ---------------- orchestration ----------------
extern "C" void kernel_launch(void* const* d_in, const int* in_sizes, int n_in,
                              void* d_out, int out_size, void* d_ws, size_t ws_size,
                              hipStream_t stream)
{
  (void)in_sizes; (void)n_in; (void)out_size;
  const float* h1     = (const float*)d_in[0];
  const float* h2     = (const float*)d_in[1];
  const float* obs    = (const float*)d_in[2];
  const unsigned char* done_raw = (const unsigned char*)d_in[3];
  const float* W_embed=(const float*)d_in[4];  const float* b_embed=(const float*)d_in[5];
  const float* Wi1    =(const float*)d_in[6];  const float* bi1    =(const float*)d_in[7];
  const float* Wh1    =(const float*)d_in[8];  const float* bhn1   =(const float*)d_in[9];
  const float* W_sub  =(const float*)d_in[10]; const float* b_sub  =(const float*)d_in[11];
  const float* W_e1   =(const float*)d_in[12]; const float* b_e1   =(const float*)d_in[13];
  const float* W_e2   =(const float*)d_in[14]; const float* b_e2   =(const float*)d_in[15];
  const float* W_pol  =(const float*)d_in[16]; const float* b_pol  =(const float*)d_in[17];
  const float* Wi2    =(const float*)d_in[18]; const float* bi2    =(const float*)d_in[19];
  const float* Wh2    =(const float*)d_in[20]; const float* bhn2   =(const float*)d_in[21];
  const float* W_w1   =(const float*)d_in[22]; const float* b_w1   =(const float*)d_in[23];
  const float* W_b1   =(const float*)d_in[24]; const float* b_b1   =(const float*)d_in[25];

  float* out    = (float*)d_out;
  float* outHT1 = out;
  float* outHT2 = out + (size_t)NB*HH;
  float* outQ   = out + 2ull*NB*HH;
  float* outLG  = outQ + (size_t)TT*NB*AA;
  float* outSE  = outLG + (size_t)TT*BB*NN*KK;

  // ---- adaptive chunk size from ws_size ----
  const size_t fixed_f = 2ull*NB*HH + (size_t)TT*NB + 1024
                       + (size_t)KK*HH*AA + 256 + (size_t)TT*NB + 64;
  const size_t per_t_f = (size_t)NB*(2*HH + 2*H3 + SS);
  int CH = 64;
  while (CH > 1 && (fixed_f + per_t_f*(size_t)CH)*4 > ws_size) CH >>= 1;

  float* buf1   = (float*)d_ws;                        // ae1/y1 chunk: CH*NB*HH
  float* buf2   = buf1   + (size_t)CH*NB*HH;           // sp/y2 chunk
  float* gbuf1  = buf2   + (size_t)CH*NB*HH;           // gi1 chunk: CH*NB*H3
  float* gbuf2  = gbuf1  + (size_t)CH*NB*H3;           // gi2 chunk
  float* ae2buf = gbuf2  + (size_t)CH*NB*H3;           // CH*NB*SS
  float* h_last1= ae2buf + (size_t)CH*NB*SS;
  float* h_last2= h_last1+ (size_t)NB*HH;
  float* maskp  = h_last2+ (size_t)NB*HH;
  float* ws_e   = maskp  + (size_t)TT*NB;
  float* ws_w1  = ws_e   + 1024;
  float* ws_b1  = ws_w1  + (size_t)KK*HH*AA;
  int*   ws_argk= (int*)(ws_b1 + 256);
  int*   ws_flag= (int*)(ws_argk + (size_t)TT*NB);

  // phase 0
  k_detect<<<1,256,0,stream>>>(done_raw, ws_flag);
  k_mask<<<TT*NB/256,256,0,stream>>>(done_raw, ws_flag, maskp);
  k_e<<<1,256,0,stream>>>(W_e1,b_e1,W_e2,b_e2,ws_e);
  k_w1b1<<<128,256,0,stream>>>(ws_e,W_w1,b_w1,W_b1,b_b1,ws_w1,ws_b1);
  k_se<<<2048,256,0,stream>>>(ws_e,outSE);
  k_copy<<<512,256,0,stream>>>(h1, h_last1, NB*HH/4);
  k_copy<<<512,256,0,stream>>>(h2, h_last2, NB*HH/4);

  dim3 thr(256);
  const int NCH = TT / CH;
  for (int c = 0; c < NCH; ++c){
    int t0 = c * CH;
    const float* obs_c = obs + (size_t)t0*NB*DD;
    gemm_bias_act<1><<<dim3(HH/64, CH*NB/64),thr,0,stream>>>(obs_c, W_embed, b_embed, buf1, CH*NB, DD, HH);
    gemm_bias_act<0><<<dim3(H3/64, CH*NB/64),thr,0,stream>>>(buf1, Wi1, bi1, gbuf1, CH*NB, HH, H3);
    gemm_bias_act<1><<<dim3(HH/64, CH*NB/64),thr,0,stream>>>(obs_c, W_pol, b_pol, buf2, CH*NB, DD, HH);
    gemm_bias_act<0><<<dim3(H3/64, CH*NB/64),thr,0,stream>>>(buf2, Wi2, bi2, gbuf2, CH*NB, HH, H3);
    // dual-GRU scan: one fused 3-gate GEMM launch per step (robust, lockstep by construction)
    for (int lt = 0; lt < CH; ++lt){
      const float* hp1 = (lt == 0) ? h_last1 : (buf1 + (size_t)(lt-1)*NB*HH);
      const float* hp2 = (lt == 0) ? h_last2 : (buf2 + (size_t)(lt-1)*NB*HH);
      gru_gemm_step<<<512, 256, 0, stream>>>(hp1, hp2,
                                             gbuf1 + (size_t)lt*NB*H3, gbuf2 + (size_t)lt*NB*H3,
                                             Wh1, Wh2, bhn1, bhn2,
                                             maskp + (size_t)(t0+lt)*NB,
                                             buf1 + (size_t)lt*NB*HH, buf2 + (size_t)lt*NB*HH);
    }
    k_copy<<<512,256,0,stream>>>(buf1 + (size_t)(CH-1)*NB*HH, h_last1, NB*HH/4);
    k_copy<<<512,256,0,stream>>>(buf2 + (size_t)(CH-1)*NB*HH, h_last2, NB*HH/4);
    gemm_bias_act<0><<<dim3(SS/64, CH*NB/64),thr,0,stream>>>(buf1, W_sub, b_sub, ae2buf, CH*NB, HH, SS);
    k_logits<<<CH*NB/256,256,0,stream>>>(ae2buf, ws_e, outLG, ws_argk, t0);
    k_qsel<<<CH*NB,64,0,stream>>>(buf2, ws_w1, ws_b1, ws_argk + (size_t)t0*NB, outQ + (size_t)t0*NB*AA);
  }
  k_copy<<<512,256,0,stream>>>(h_last1, outHT1, NB*HH/4);
  k_copy<<<512,256,0,stream>>>(h_last2, outHT2, NB*HH/4);
}

// Round 8
// 7249.263 us; speedup vs baseline: 3.3132x; 1.1077x over previous
//
#include <hip/hip_runtime.h>
#include <hip/hip_bf16.h>
#include <math.h>

#define TT 64
#define NN 8
#define BB 128
#define DD 128
#define HH 512
#define SS 64
#define KK 16
#define AA 16
#define NB 1024
#define H3 (3*HH)       /* 1536 */

typedef float f4v __attribute__((ext_vector_type(4)));
typedef short bf16x8 __attribute__((ext_vector_type(8)));

__device__ __forceinline__ float sigm(float x){ return 1.0f/(1.0f+expf(-x)); }
__device__ __forceinline__ unsigned short f2bf(float f){
  unsigned u = __float_as_uint(f);
  u += 0x7FFF + ((u >> 16) & 1);          // round-to-nearest-even
  return (unsigned short)(u >> 16);
}

// ---------------- done-layout detection + mask expansion ----------------
__global__ __launch_bounds__(256) void k_detect(const unsigned char* __restrict__ raw,
                                                int* __restrict__ flag)
{
  __shared__ int cA, cB;
  if (threadIdx.x == 0){ cA = 0; cB = 0; }
  __syncthreads();
  int a = 0, b = 0;
  for (int i = threadIdx.x; i < TT*NB; i += 256){
    unsigned char v = raw[i];
    if (v > 1) a++;
    if ((i & 3) != 0 && v != 0) b++;
  }
  atomicAdd(&cA, a); atomicAdd(&cB, b);
  __syncthreads();
  if (threadIdx.x == 0) *flag = (cB == 0) ? 0 : (cA == 0 ? 1 : 2);
}

__global__ __launch_bounds__(256) void k_mask(const unsigned char* __restrict__ raw,
                                              const int* __restrict__ flag,
                                              float* __restrict__ mask)
{
  int i = blockIdx.x*256 + threadIdx.x;
  if (i >= TT*NB) return;
  int f = *flag;
  int v;
  if (f == 1)      v = (int)raw[i];
  else if (f == 0) v = ((const int*)raw)[i];
  else             v = (((const float*)raw)[i] != 0.0f);
  mask[i] = v ? 0.f : 1.f;   // 0 => reset carry
}

// ---------------- small setup kernels ----------------

__global__ __launch_bounds__(256) void k_e(const float* __restrict__ W_e1, const float* __restrict__ b_e1,
                                           const float* __restrict__ W_e2, const float* __restrict__ b_e2,
                                           float* __restrict__ e_out)
{
  __shared__ float r1[KK*SS];
  int tid = threadIdx.x;
  for (int i=0;i<4;++i){ int l = tid + i*256; float v = W_e1[l] + b_e1[l & 63]; r1[l] = v > 0.f ? v : 0.f; }
  __syncthreads();
  for (int i=0;i<4;++i){
    int l = tid + i*256; int k = l >> 6, s = l & 63;
    float acc = b_e2[s];
    #pragma unroll 8
    for (int sp=0; sp<64; ++sp) acc += r1[k*64+sp] * W_e2[sp*64 + s];
    e_out[l] = tanhf(acc);
  }
}

__global__ __launch_bounds__(256) void k_w1b1(const float* __restrict__ e, const float* __restrict__ W_w1,
                                              const float* __restrict__ b_w1, const float* __restrict__ W_b1,
                                              const float* __restrict__ b_b1, float* __restrict__ w1,
                                              float* __restrict__ b1)
{
  __shared__ float es[KK*SS];
  int tid = threadIdx.x;
  for (int i=0;i<4;++i) es[tid + i*256] = e[tid + i*256];
  __syncthreads();
  for (int i=0;i<4;++i){
    int l = blockIdx.x*1024 + tid + i*256;
    int k = l >> 13, m = l & 8191;
    float acc = b_w1[m];
    #pragma unroll 8
    for (int s=0;s<64;++s) acc += es[k*64+s] * W_w1[(size_t)s*8192 + m];
    w1[l] = acc;
  }
  if (blockIdx.x == 0){
    int k = tid >> 4, a = tid & 15;
    float acc = b_b1[a];
    #pragma unroll 8
    for (int s=0;s<64;++s) acc += es[k*64+s] * W_b1[s*16 + a];
    b1[tid] = acc;
  }
}

__global__ __launch_bounds__(256) void k_se(const float* __restrict__ e, float* __restrict__ outse)
{
  __shared__ float4 es[256];
  es[threadIdx.x] = ((const float4*)e)[threadIdx.x];
  __syncthreads();
  const int total4 = TT*BB*KK*SS/4;
  for (int i = blockIdx.x*256 + threadIdx.x; i < total4; i += gridDim.x*256)
    ((float4*)outse)[i] = es[i & 255];
}

__global__ void k_copy(const float* __restrict__ src, float* __restrict__ dst, int n4)
{
  int i = blockIdx.x*blockDim.x + threadIdx.x;
  if (i < n4) ((float4*)dst)[i] = ((const float4*)src)[i];
}

// W f32 [512][1536] -> WT bf16 [1536][512]
__global__ __launch_bounds__(256) void k_transpose_bf16(const float* __restrict__ W,
                                                        unsigned short* __restrict__ WT)
{
  __shared__ float t[32][33];
  int n0 = blockIdx.x * 32;
  int k0 = blockIdx.y * 32;
  int c = threadIdx.x & 31, r8 = threadIdx.x >> 5;
  for (int i=0;i<4;++i){
    int r = r8 + i*8;
    t[r][c] = W[(size_t)(k0+r)*H3 + n0 + c];
  }
  __syncthreads();
  for (int i=0;i<4;++i){
    int nr = r8 + i*8;
    WT[(size_t)(n0+nr)*HH + k0 + c] = f2bf(t[c][nr]);
  }
}

// f32 -> bf16 flat cast (8 elems/thread)
__global__ void k_cast_bf16(const float* __restrict__ src, unsigned short* __restrict__ dst, int n8)
{
  int i = blockIdx.x*blockDim.x + threadIdx.x;
  if (i >= n8) return;
  const float4* s = (const float4*)(src + (size_t)i*8);
  float4 a = s[0], b = s[1];
  union { unsigned short u[8]; uint4 v; } p;
  p.u[0]=f2bf(a.x); p.u[1]=f2bf(a.y); p.u[2]=f2bf(a.z); p.u[3]=f2bf(a.w);
  p.u[4]=f2bf(b.x); p.u[5]=f2bf(b.y); p.u[6]=f2bf(b.z); p.u[7]=f2bf(b.w);
  *(uint4*)&dst[(size_t)i*8] = p.v;
}

// ---------------- generic tiled f32 GEMM: C = act(A@W + bias) ----------------
template<int RELU>
__global__ __launch_bounds__(256) void gemm_bias_act(
    const float* __restrict__ A, const float* __restrict__ W,
    const float* __restrict__ bias, float* __restrict__ C,
    int M, int Kd, int Nc)
{
  __shared__ float As[16][72];
  __shared__ float Bs[16][72];
  int tid = threadIdx.x;
  int tx = tid & 15, ty = tid >> 4;
  int rowBase = blockIdx.y * 64;
  int colBase = blockIdx.x * 64;
  float acc[4][4] = {};
  for (int k0 = 0; k0 < Kd; k0 += 16){
    {
      int r  = tid >> 2;
      int kb = (tid & 3) * 4;
      float4 v = *(const float4*)&A[(size_t)(rowBase + r)*Kd + k0 + kb];
      As[kb+0][r]=v.x; As[kb+1][r]=v.y; As[kb+2][r]=v.z; As[kb+3][r]=v.w;
    }
    #pragma unroll
    for (int i=0;i<4;++i){
      int l = i*256 + tid;
      int kk = l >> 6, c = l & 63;
      Bs[kk][c] = W[(size_t)(k0+kk)*Nc + colBase + c];
    }
    __syncthreads();
    #pragma unroll
    for (int kk=0;kk<16;++kk){
      float4 a4 = *(const float4*)&As[kk][ty*4];
      float4 b4 = *(const float4*)&Bs[kk][tx*4];
      float av[4]={a4.x,a4.y,a4.z,a4.w}, bv[4]={b4.x,b4.y,b4.z,b4.w};
      #pragma unroll
      for (int i=0;i<4;++i)
        #pragma unroll
        for (int j=0;j<4;++j) acc[i][j] += av[i]*bv[j];
    }
    __syncthreads();
  }
  int c0 = colBase + tx*4;
  float4 bv4 = *(const float4*)&bias[c0];
  float bb[4]={bv4.x,bv4.y,bv4.z,bv4.w};
  for (int i=0;i<4;++i){
    int r = rowBase + ty*4 + i;
    float o[4];
    #pragma unroll
    for (int j=0;j<4;++j){ float v = acc[i][j] + bb[j]; if (RELU) v = v>0.f?v:0.f; o[j]=v; }
    *(float4*)&C[(size_t)r*Nc + c0] = make_float4(o[0],o[1],o[2],o[3]);
  }
}

// ---------------- bf16 MFMA GEMM: C = A@W + bias  (A pre-cast bf16, W pre-transposed bf16) ----------------
// 128x128 tile, 256 thr = 4 waves; wave: 2 row-frags x 8 col-frags of 16x16x32.
__global__ __launch_bounds__(256) void mfma_gemm_bias(
    const unsigned short* __restrict__ Abf, const unsigned short* __restrict__ WT,
    const float* __restrict__ bias, float* __restrict__ C)
{
  __shared__ __align__(16) unsigned short As[128*40];
  __shared__ __align__(16) unsigned short Bs[128*40];
  int tid = threadIdx.x;
  int w = tid >> 6, l = tid & 63;
  int lr = l & 15, lk = (l >> 4) * 8, lq = l >> 4;
  int rowBase = blockIdx.y * 128, colBase = blockIdx.x * 128;
  f4v acc[2][8];
  f4v z = {0.f,0.f,0.f,0.f};
  #pragma unroll
  for (int i=0;i<2;++i)
    #pragma unroll
    for (int j=0;j<8;++j) acc[i][j] = z;

  for (int k0 = 0; k0 < HH; k0 += 32){
    {
      int r = tid >> 1, half = tid & 1;
      const bf16x8* sA = (const bf16x8*)&Abf[(size_t)(rowBase + r)*HH + k0 + half*16];
      bf16x8* dA = (bf16x8*)&As[r*40 + half*16];
      dA[0] = sA[0]; dA[1] = sA[1];
      const bf16x8* sB = (const bf16x8*)&WT[(size_t)(colBase + r)*HH + k0 + half*16];
      bf16x8* dB = (bf16x8*)&Bs[r*40 + half*16];
      dB[0] = sB[0]; dB[1] = sB[1];
    }
    __syncthreads();
    bf16x8 a0 = *(const bf16x8*)&As[(w*32 + lr)*40 + lk];
    bf16x8 a1 = *(const bf16x8*)&As[(w*32 + 16 + lr)*40 + lk];
    #pragma unroll
    for (int fc=0; fc<8; ++fc){
      bf16x8 b = *(const bf16x8*)&Bs[(fc*16 + lr)*40 + lk];
      acc[0][fc] = __builtin_amdgcn_mfma_f32_16x16x32_bf16(a0, b, acc[0][fc], 0,0,0);
      acc[1][fc] = __builtin_amdgcn_mfma_f32_16x16x32_bf16(a1, b, acc[1][fc], 0,0,0);
    }
    __syncthreads();
  }
  #pragma unroll
  for (int fr=0; fr<2; ++fr){
    #pragma unroll
    for (int fc=0; fc<8; ++fc){
      int col = colBase + fc*16 + lr;
      float bv = bias[col];
      #pragma unroll
      for (int r=0;r<4;++r){
        int row = rowBase + w*32 + fr*16 + lq*4 + r;
        C[(size_t)row*H3 + col] = acc[fr][fc][r] + bv;
      }
    }
  }
}

// ---------------- mixed per-step GRU: blocks 0-127 = bf16-MFMA GRU2, 128-383 = fp32 GRU1 ----------------
__global__ __launch_bounds__(256) void gru_step_mix(
    const float* __restrict__ hp1, const float* __restrict__ hp2,
    const float* __restrict__ gi1, const float* __restrict__ gi2,
    const float* __restrict__ Wh1, const unsigned short* __restrict__ Wh2T,
    const float* __restrict__ bhn1, const float* __restrict__ bhn2,
    const float* __restrict__ mask_t,
    float* __restrict__ ho1, float* __restrict__ ho2)
{
  __shared__ __align__(16) char smem[20992];
  int bid = blockIdx.x;
  int tid = threadIdx.x;

  if (bid < 128){
    // ===== bf16 MFMA path: GRU2. tile 64 rows x (3 gates x 64 h-cols) =====
    unsigned short* As = (unsigned short*)smem;            // [64][40]
    unsigned short* Bs = (unsigned short*)smem + 64*40;    // [192][40]
    int ct = bid & 7, rt = bid >> 3;
    int rowBase = rt << 6, colBase = ct << 6;
    int w = tid >> 6, l = tid & 63;
    int lr = l & 15, lk = (l >> 4) * 8, lq = l >> 4;
    f4v acc[12];
    f4v z = {0.f,0.f,0.f,0.f};
    #pragma unroll
    for (int i=0;i<12;++i) acc[i] = z;

    for (int k0 = 0; k0 < HH; k0 += 32){
      // stage A: 64 rows x 32 k of masked h2, f32 -> bf16
      {
        int r = tid >> 2, grp = tid & 3;
        float m = mask_t[rowBase + r];
        const float4* s = (const float4*)&hp2[(size_t)(rowBase + r)*HH + k0 + grp*8];
        float4 v0 = s[0], v1 = s[1];
        union { unsigned short u[8]; uint4 v; } p;
        p.u[0]=f2bf(v0.x*m); p.u[1]=f2bf(v0.y*m); p.u[2]=f2bf(v0.z*m); p.u[3]=f2bf(v0.w*m);
        p.u[4]=f2bf(v1.x*m); p.u[5]=f2bf(v1.y*m); p.u[6]=f2bf(v1.z*m); p.u[7]=f2bf(v1.w*m);
        *(uint4*)&As[r*40 + grp*8] = p.v;
      }
      // stage B: 192 gate-cols x 32 k from Wh2T (bf16, [gatecol][k])
      #pragma unroll
      for (int i=0;i<3;++i){
        int unit = i*256 + tid;          // 768 x 16B
        int brow = unit >> 2, q = unit & 3;
        int g = brow >> 6, c = brow & 63;
        *(bf16x8*)&Bs[brow*40 + q*8] =
            *(const bf16x8*)&Wh2T[(size_t)(g*HH + colBase + c)*HH + k0 + q*8];
      }
      __syncthreads();
      bf16x8 a = *(const bf16x8*)&As[(w*16 + lr)*40 + lk];
      #pragma unroll
      for (int cf=0; cf<12; ++cf){
        bf16x8 b = *(const bf16x8*)&Bs[(cf*16 + lr)*40 + lk];
        acc[cf] = __builtin_amdgcn_mfma_f32_16x16x32_bf16(a, b, acc[cf], 0,0,0);
      }
      __syncthreads();
    }
    // fp32 gate epilogue
    #pragma unroll
    for (int f=0; f<4; ++f){
      int hcol = colBase + f*16 + lr;
      float bn = bhn2[hcol];
      #pragma unroll
      for (int r=0;r<4;++r){
        int row = rowBase + w*16 + lq*4 + r;
        size_t gb = (size_t)row*H3 + hcol;
        float g_r = __builtin_nontemporal_load(&gi2[gb]);
        float g_z = __builtin_nontemporal_load(&gi2[gb + HH]);
        float g_n = __builtin_nontemporal_load(&gi2[gb + 2*HH]);
        float hv  = hp2[(size_t)row*HH + hcol] * mask_t[row];
        float rg = sigm(g_r + acc[f][r]);
        float zg = sigm(g_z + acc[4+f][r]);
        float ng = tanhf(g_n + rg*(acc[8+f][r] + bn));
        ho2[(size_t)row*HH + hcol] = (1.f - zg)*ng + zg*hv;
      }
    }
  } else {
    // ===== fp32 path: GRU1 (verbatim round-7 tile, 32 rows x 64 cols x 3 gates) =====
    float (*As)[40]    = (float(*)[40])smem;                  // 16x40
    float (*Bs)[3][68] = (float(*)[3][68])(smem + 2560);      // 16x3x68
    float* dms         = (float*)(smem + 2560 + 13056);       // 32
    int bidp = bid - 128;
    int ct = bidp & 7, rt = bidp >> 3;
    int rowBase = rt << 5;
    int colBase = ct << 6;
    int tx = tid & 15, ty = tid >> 4;

    if (tid < 32) dms[tid] = mask_t[rowBase + tid];
    __syncthreads();

    float acc[3][2][4] = {};
    float hval[2][4];

    for (int k0 = 0; k0 < HH; k0 += 16){
      {
        int r = tid >> 3, kb = (tid & 7) * 2;
        float m = dms[r];
        float2 v = *(const float2*)&hp1[(size_t)(rowBase + r)*HH + k0 + kb];
        As[kb+0][r] = v.x * m;
        As[kb+1][r] = v.y * m;
      }
      #pragma unroll
      for (int i=0;i<12;++i){
        int lidx = i*256 + tid;
        int c = lidx & 63, t = lidx >> 6;
        int g = t % 3, kk = t / 3;
        Bs[kk][g][c] = Wh1[(size_t)(k0+kk)*H3 + g*HH + colBase + c];
      }
      __syncthreads();
      if (k0 - colBase == ((tx >> 2) << 4)){
        #pragma unroll
        for (int i=0;i<2;++i)
          #pragma unroll
          for (int j=0;j<4;++j)
            hval[i][j] = As[(tx & 3)*4 + j][ty*2 + i];
      }
      #pragma unroll
      for (int kk=0;kk<16;++kk){
        float2 a2 = *(const float2*)&As[kk][ty*2];
        float4 b0 = *(const float4*)&Bs[kk][0][tx*4];
        float4 b1 = *(const float4*)&Bs[kk][1][tx*4];
        float4 b2 = *(const float4*)&Bs[kk][2][tx*4];
        float av[2] = {a2.x, a2.y};
        float b0v[4]={b0.x,b0.y,b0.z,b0.w};
        float b1v[4]={b1.x,b1.y,b1.z,b1.w};
        float b2v[4]={b2.x,b2.y,b2.z,b2.w};
        #pragma unroll
        for (int i=0;i<2;++i)
          #pragma unroll
          for (int j=0;j<4;++j){
            acc[0][i][j] += av[i]*b0v[j];
            acc[1][i][j] += av[i]*b1v[j];
            acc[2][i][j] += av[i]*b2v[j];
          }
      }
      __syncthreads();
    }

    int c0 = colBase + tx*4;
    float4 bn4 = *(const float4*)&bhn1[c0];
    float bnv[4] = {bn4.x, bn4.y, bn4.z, bn4.w};
    #pragma unroll
    for (int i=0;i<2;++i){
      int row = rowBase + ty*2 + i;
      size_t gb = (size_t)row*H3 + c0;
      f4v g_r = __builtin_nontemporal_load((const f4v*)&gi1[gb]);
      f4v g_z = __builtin_nontemporal_load((const f4v*)&gi1[gb + HH]);
      f4v g_n = __builtin_nontemporal_load((const f4v*)&gi1[gb + 2*HH]);
      float o[4];
      #pragma unroll
      for (int j=0;j<4;++j){
        float rg = sigm(g_r[j] + acc[0][i][j]);
        float zg = sigm(g_z[j] + acc[1][i][j]);
        float ng = tanhf(g_n[j] + rg*(acc[2][i][j] + bnv[j]));
        o[j] = (1.f - zg)*ng + zg*hval[i][j];
      }
      *(float4*)&ho1[(size_t)row*HH + c0] = make_float4(o[0],o[1],o[2],o[3]);
    }
  }
}

// ---------------- logits + first-max argmax (chunked: t = t0 + local) ----------------
__global__ __launch_bounds__(256) void k_logits(const float* __restrict__ ae2,
    const float* __restrict__ e, float* __restrict__ out_logits, int* __restrict__ argk, int t0)
{
  __shared__ float es[KK*SS];
  int tid = threadIdx.x;
  for (int i=0;i<4;++i) es[tid + i*256] = e[tid + i*256];
  __syncthreads();
  int g = blockIdx.x*256 + tid;
  int t = t0 + (g >> 10), j = g & 1023;
  const float* arow = &ae2[(size_t)g * SS];
  float a[SS];
  #pragma unroll
  for (int i=0;i<16;++i){ float4 v = ((const float4*)arow)[i]; a[4*i]=v.x; a[4*i+1]=v.y; a[4*i+2]=v.z; a[4*i+3]=v.w; }
  float lg[KK];
  float best = -INFINITY; int bk = 0;
  for (int k=0;k<KK;++k){
    float s2 = 0.f;
    #pragma unroll 8
    for (int s=0;s<SS;++s) s2 += a[s]*es[k*SS+s];
    lg[k] = s2;
    if (s2 > best){ best = s2; bk = k; }
  }
  int n = j >> 7, b = j & 127;
  size_t ob = ((size_t)((t*BB + b)*NN + n)) * KK;
  #pragma unroll
  for (int k4=0;k4<4;++k4)
    *(float4*)&out_logits[ob + k4*4] = make_float4(lg[k4*4],lg[k4*4+1],lg[k4*4+2],lg[k4*4+3]);
  argk[(t*BB + b)*NN + n] = bk;   // (b,n)-major: matches reference's prob/q index quirk
}

// ---------------- q selection (chunked) ----------------
__global__ __launch_bounds__(64) void k_qsel(const float* __restrict__ y2,
    const float* __restrict__ w1, const float* __restrict__ b1,
    const int* __restrict__ argk, float* __restrict__ outq)
{
  __shared__ float yr[HH];
  __shared__ float part[64];
  int bj = blockIdx.x;
  int tid = threadIdx.x;
  const float4* row4 = (const float4*)&y2[(size_t)bj*HH];
  ((float4*)yr)[tid]    = row4[tid];
  ((float4*)yr)[tid+64] = row4[tid+64];
  __syncthreads();
  int k = argk[bj];
  int a = tid & 15, q4 = tid >> 4;
  const float* wp = &w1[(size_t)k*HH*AA + a];
  float s = 0.f;
  int h0 = q4*128;
  #pragma unroll 8
  for (int h=h0; h<h0+128; ++h) s += yr[h]*wp[(size_t)h*AA];
  part[tid] = s;
  __syncthreads();
  if (q4 == 0){
    float v = part[a] + part[a+16] + part[a+32] + part[a+48] + b1[k*AA + a];
    outq[(size_t)bj*AA + a] = v;
  }
}

// ---------------- orchestration ----------------
extern "C" void kernel_launch(void* const* d_in, const int* in_sizes, int n_in,
                              void* d_out, int out_size, void* d_ws, size_t ws_size,
                              hipStream_t stream)
{
  (void)in_sizes; (void)n_in; (void)out_size;
  const float* h1     = (const float*)d_in[0];
  const float* h2     = (const float*)d_in[1];
  const float* obs    = (const float*)d_in[2];
  const unsigned char* done_raw = (const unsigned char*)d_in[3];
  const float* W_embed=(const float*)d_in[4];  const float* b_embed=(const float*)d_in[5];
  const float* Wi1    =(const float*)d_in[6];  const float* bi1    =(const float*)d_in[7];
  const float* Wh1    =(const float*)d_in[8];  const float* bhn1   =(const float*)d_in[9];
  const float* W_sub  =(const float*)d_in[10]; const float* b_sub  =(const float*)d_in[11];
  const float* W_e1   =(const float*)d_in[12]; const float* b_e1   =(const float*)d_in[13];
  const float* W_e2   =(const float*)d_in[14]; const float* b_e2   =(const float*)d_in[15];
  const float* W_pol  =(const float*)d_in[16]; const float* b_pol  =(const float*)d_in[17];
  const float* Wi2    =(const float*)d_in[18]; const float* bi2    =(const float*)d_in[19];
  const float* Wh2    =(const float*)d_in[20]; const float* bhn2   =(const float*)d_in[21];
  const float* W_w1   =(const float*)d_in[22]; const float* b_w1   =(const float*)d_in[23];
  const float* W_b1   =(const float*)d_in[24]; const float* b_b1   =(const float*)d_in[25];

  float* out    = (float*)d_out;
  float* outHT1 = out;
  float* outHT2 = out + (size_t)NB*HH;
  float* outQ   = out + 2ull*NB*HH;
  float* outLG  = outQ + (size_t)TT*NB*AA;
  float* outSE  = outLG + (size_t)TT*BB*NN*KK;

  // ---- adaptive chunk size from ws_size (float units; includes bf16 buffers) ----
  const size_t fixed_f = 2ull*NB*HH + (size_t)TT*NB + 1024
                       + (size_t)KK*HH*AA + 256 + (size_t)TT*NB + 64
                       + 2ull*H3*HH/2;                  // Wi2T + Wh2T (bf16)
  const size_t per_t_f = (size_t)NB*(2*HH + 2*H3 + SS) + (size_t)NB*HH/2;  // + buf2bf
  int CH = 64;
  while (CH > 1 && (fixed_f + per_t_f*(size_t)CH)*4 > ws_size) CH >>= 1;

  float* buf1   = (float*)d_ws;                        // ae1/y1 chunk: CH*NB*HH
  float* buf2   = buf1   + (size_t)CH*NB*HH;           // sp/y2 chunk
  float* gbuf1  = buf2   + (size_t)CH*NB*HH;           // gi1 chunk: CH*NB*H3
  float* gbuf2  = gbuf1  + (size_t)CH*NB*H3;           // gi2 chunk
  float* ae2buf = gbuf2  + (size_t)CH*NB*H3;           // CH*NB*SS
  float* h_last1= ae2buf + (size_t)CH*NB*SS;
  float* h_last2= h_last1+ (size_t)NB*HH;
  float* maskp  = h_last2+ (size_t)NB*HH;
  float* ws_e   = maskp  + (size_t)TT*NB;
  float* ws_w1  = ws_e   + 1024;
  float* ws_b1  = ws_w1  + (size_t)KK*HH*AA;
  int*   ws_argk= (int*)(ws_b1 + 256);
  int*   ws_flag= (int*)(ws_argk + (size_t)TT*NB);
  unsigned short* buf2bf = (unsigned short*)(ws_flag + 64);   // CH*NB*HH bf16
  unsigned short* wi2t   = buf2bf + (size_t)CH*NB*HH;         // 1536*512 bf16
  unsigned short* wh2t   = wi2t   + (size_t)H3*HH;            // 1536*512 bf16

  // phase 0
  k_detect<<<1,256,0,stream>>>(done_raw, ws_flag);
  k_mask<<<TT*NB/256,256,0,stream>>>(done_raw, ws_flag, maskp);
  k_e<<<1,256,0,stream>>>(W_e1,b_e1,W_e2,b_e2,ws_e);
  k_w1b1<<<128,256,0,stream>>>(ws_e,W_w1,b_w1,W_b1,b_b1,ws_w1,ws_b1);
  k_se<<<2048,256,0,stream>>>(ws_e,outSE);
  k_transpose_bf16<<<dim3(48,16),256,0,stream>>>(Wi2, wi2t);
  k_transpose_bf16<<<dim3(48,16),256,0,stream>>>(Wh2, wh2t);
  k_copy<<<512,256,0,stream>>>(h1, h_last1, NB*HH/4);
  k_copy<<<512,256,0,stream>>>(h2, h_last2, NB*HH/4);

  dim3 thr(256);
  const int NCH = TT / CH;
  for (int c = 0; c < NCH; ++c){
    int t0 = c * CH;
    const float* obs_c = obs + (size_t)t0*NB*DD;
    // branch-1 front (exact fp32)
    gemm_bias_act<1><<<dim3(HH/64, CH*NB/64),thr,0,stream>>>(obs_c, W_embed, b_embed, buf1, CH*NB, DD, HH);
    gemm_bias_act<0><<<dim3(H3/64, CH*NB/64),thr,0,stream>>>(buf1, Wi1, bi1, gbuf1, CH*NB, HH, H3);
    // branch-2 front (bf16 MFMA for gi2)
    gemm_bias_act<1><<<dim3(HH/64, CH*NB/64),thr,0,stream>>>(obs_c, W_pol, b_pol, buf2, CH*NB, DD, HH);
    {
      int n8 = CH*NB*HH/8;
      k_cast_bf16<<<(n8+255)/256,256,0,stream>>>(buf2, buf2bf, n8);
    }
    mfma_gemm_bias<<<dim3(H3/128, CH*NB/128),thr,0,stream>>>(buf2bf, wi2t, bi2, gbuf2);
    // dual-GRU scan: mixed fp32(GRU1)/MFMA(GRU2) launch per step
    for (int lt = 0; lt < CH; ++lt){
      const float* hp1 = (lt == 0) ? h_last1 : (buf1 + (size_t)(lt-1)*NB*HH);
      const float* hp2 = (lt == 0) ? h_last2 : (buf2 + (size_t)(lt-1)*NB*HH);
      gru_step_mix<<<384, 256, 0, stream>>>(hp1, hp2,
                                            gbuf1 + (size_t)lt*NB*H3, gbuf2 + (size_t)lt*NB*H3,
                                            Wh1, wh2t, bhn1, bhn2,
                                            maskp + (size_t)(t0+lt)*NB,
                                            buf1 + (size_t)lt*NB*HH, buf2 + (size_t)lt*NB*HH);
    }
    k_copy<<<512,256,0,stream>>>(buf1 + (size_t)(CH-1)*NB*HH, h_last1, NB*HH/4);
    k_copy<<<512,256,0,stream>>>(buf2 + (size_t)(CH-1)*NB*HH, h_last2, NB*HH/4);
    // tails
    gemm_bias_act<0><<<dim3(SS/64, CH*NB/64),thr,0,stream>>>(buf1, W_sub, b_sub, ae2buf, CH*NB, HH, SS);
    k_logits<<<CH*NB/256,256,0,stream>>>(ae2buf, ws_e, outLG, ws_argk, t0);
    k_qsel<<<CH*NB,64,0,stream>>>(buf2, ws_w1, ws_b1, ws_argk + (size_t)t0*NB, outQ + (size_t)t0*NB*AA);
  }
  k_copy<<<512,256,0,stream>>>(h_last1, outHT1, NB*HH/4);
  k_copy<<<512,256,0,stream>>>(h_last2, outHT2, NB*HH/4);
}

// Round 9
// 5771.489 us; speedup vs baseline: 4.1615x; 1.2560x over previous
//
#include <hip/hip_runtime.h>
#include <hip/hip_bf16.h>
#include <math.h>

#define TT 64
#define NN 8
#define BB 128
#define DD 128
#define HH 512
#define SS 64
#define KK 16
#define AA 16
#define NB 1024
#define H3 (3*HH)       /* 1536 */

typedef float f4v __attribute__((ext_vector_type(4)));
typedef short bf16x8 __attribute__((ext_vector_type(8)));

__device__ __forceinline__ float sigm(float x){ return 1.0f/(1.0f+expf(-x)); }
__device__ __forceinline__ unsigned short f2bf(float f){
  unsigned u = __float_as_uint(f);
  u += 0x7FFF + ((u >> 16) & 1);          // round-to-nearest-even
  return (unsigned short)(u >> 16);
}
__device__ __forceinline__ float bf2f(unsigned short h){
  return __uint_as_float(((unsigned)h) << 16);
}

// ---------------- done-layout detection + mask expansion ----------------
__global__ __launch_bounds__(256) void k_detect(const unsigned char* __restrict__ raw,
                                                int* __restrict__ flag)
{
  __shared__ int cA, cB;
  if (threadIdx.x == 0){ cA = 0; cB = 0; }
  __syncthreads();
  int a = 0, b = 0;
  for (int i = threadIdx.x; i < TT*NB; i += 256){
    unsigned char v = raw[i];
    if (v > 1) a++;
    if ((i & 3) != 0 && v != 0) b++;
  }
  atomicAdd(&cA, a); atomicAdd(&cB, b);
  __syncthreads();
  if (threadIdx.x == 0) *flag = (cB == 0) ? 0 : (cA == 0 ? 1 : 2);
}

__global__ __launch_bounds__(256) void k_mask(const unsigned char* __restrict__ raw,
                                              const int* __restrict__ flag,
                                              float* __restrict__ mask)
{
  int i = blockIdx.x*256 + threadIdx.x;
  if (i >= TT*NB) return;
  int f = *flag;
  int v;
  if (f == 1)      v = (int)raw[i];
  else if (f == 0) v = ((const int*)raw)[i];
  else             v = (((const float*)raw)[i] != 0.0f);
  mask[i] = v ? 0.f : 1.f;   // 0 => reset carry
}

// ---------------- small setup kernels ----------------

__global__ __launch_bounds__(256) void k_e(const float* __restrict__ W_e1, const float* __restrict__ b_e1,
                                           const float* __restrict__ W_e2, const float* __restrict__ b_e2,
                                           float* __restrict__ e_out)
{
  __shared__ float r1[KK*SS];
  int tid = threadIdx.x;
  for (int i=0;i<4;++i){ int l = tid + i*256; float v = W_e1[l] + b_e1[l & 63]; r1[l] = v > 0.f ? v : 0.f; }
  __syncthreads();
  for (int i=0;i<4;++i){
    int l = tid + i*256; int k = l >> 6, s = l & 63;
    float acc = b_e2[s];
    #pragma unroll 8
    for (int sp=0; sp<64; ++sp) acc += r1[k*64+sp] * W_e2[sp*64 + s];
    e_out[l] = tanhf(acc);
  }
}

__global__ __launch_bounds__(256) void k_w1b1(const float* __restrict__ e, const float* __restrict__ W_w1,
                                              const float* __restrict__ b_w1, const float* __restrict__ W_b1,
                                              const float* __restrict__ b_b1, float* __restrict__ w1,
                                              float* __restrict__ b1)
{
  __shared__ float es[KK*SS];
  int tid = threadIdx.x;
  for (int i=0;i<4;++i) es[tid + i*256] = e[tid + i*256];
  __syncthreads();
  for (int i=0;i<4;++i){
    int l = blockIdx.x*1024 + tid + i*256;
    int k = l >> 13, m = l & 8191;
    float acc = b_w1[m];
    #pragma unroll 8
    for (int s=0;s<64;++s) acc += es[k*64+s] * W_w1[(size_t)s*8192 + m];
    w1[l] = acc;
  }
  if (blockIdx.x == 0){
    int k = tid >> 4, a = tid & 15;
    float acc = b_b1[a];
    #pragma unroll 8
    for (int s=0;s<64;++s) acc += es[k*64+s] * W_b1[s*16 + a];
    b1[tid] = acc;
  }
}

__global__ __launch_bounds__(256) void k_se(const float* __restrict__ e, float* __restrict__ outse)
{
  __shared__ float4 es[256];
  es[threadIdx.x] = ((const float4*)e)[threadIdx.x];
  __syncthreads();
  const int total4 = TT*BB*KK*SS/4;
  for (int i = blockIdx.x*256 + threadIdx.x; i < total4; i += gridDim.x*256)
    ((float4*)outse)[i] = es[i & 255];
}

__global__ void k_copy(const float* __restrict__ src, float* __restrict__ dst, int n4)
{
  int i = blockIdx.x*blockDim.x + threadIdx.x;
  if (i < n4) ((float4*)dst)[i] = ((const float4*)src)[i];
}

// W f32 [512][1536] -> WT bf16 [1536][512]
__global__ __launch_bounds__(256) void k_transpose_bf16(const float* __restrict__ W,
                                                        unsigned short* __restrict__ WT)
{
  __shared__ float t[32][33];
  int n0 = blockIdx.x * 32;
  int k0 = blockIdx.y * 32;
  int c = threadIdx.x & 31, r8 = threadIdx.x >> 5;
  for (int i=0;i<4;++i){
    int r = r8 + i*8;
    t[r][c] = W[(size_t)(k0+r)*H3 + n0 + c];
  }
  __syncthreads();
  for (int i=0;i<4;++i){
    int nr = r8 + i*8;
    WT[(size_t)(n0+nr)*HH + k0 + c] = f2bf(t[c][nr]);
  }
}

// W f32 [512][1536] -> WT_hi/WT_lo bf16 [1536][512] (split: hi = bf16(x), lo = bf16(x-hi))
__global__ __launch_bounds__(256) void k_transpose_split(const float* __restrict__ W,
                                                         unsigned short* __restrict__ WT_hi,
                                                         unsigned short* __restrict__ WT_lo)
{
  __shared__ float t[32][33];
  int n0 = blockIdx.x * 32;
  int k0 = blockIdx.y * 32;
  int c = threadIdx.x & 31, r8 = threadIdx.x >> 5;
  for (int i=0;i<4;++i){
    int r = r8 + i*8;
    t[r][c] = W[(size_t)(k0+r)*H3 + n0 + c];
  }
  __syncthreads();
  for (int i=0;i<4;++i){
    int nr = r8 + i*8;
    float v = t[c][nr];
    unsigned short hi = f2bf(v);
    unsigned short lo = f2bf(v - bf2f(hi));
    WT_hi[(size_t)(n0+nr)*HH + k0 + c] = hi;
    WT_lo[(size_t)(n0+nr)*HH + k0 + c] = lo;
  }
}

// ---------------- generic tiled f32 GEMM: C = act(A@W + bias); OUTBF writes bf16 ----------------
template<int RELU, int OUTBF>
__global__ __launch_bounds__(256) void gemm_bias_act(
    const float* __restrict__ A, const float* __restrict__ W,
    const float* __restrict__ bias, float* __restrict__ C,
    int M, int Kd, int Nc)
{
  __shared__ float As[16][72];
  __shared__ float Bs[16][72];
  int tid = threadIdx.x;
  int tx = tid & 15, ty = tid >> 4;
  int rowBase = blockIdx.y * 64;
  int colBase = blockIdx.x * 64;
  float acc[4][4] = {};
  for (int k0 = 0; k0 < Kd; k0 += 16){
    {
      int r  = tid >> 2;
      int kb = (tid & 3) * 4;
      float4 v = *(const float4*)&A[(size_t)(rowBase + r)*Kd + k0 + kb];
      As[kb+0][r]=v.x; As[kb+1][r]=v.y; As[kb+2][r]=v.z; As[kb+3][r]=v.w;
    }
    #pragma unroll
    for (int i=0;i<4;++i){
      int l = i*256 + tid;
      int kk = l >> 6, c = l & 63;
      Bs[kk][c] = W[(size_t)(k0+kk)*Nc + colBase + c];
    }
    __syncthreads();
    #pragma unroll
    for (int kk=0;kk<16;++kk){
      float4 a4 = *(const float4*)&As[kk][ty*4];
      float4 b4 = *(const float4*)&Bs[kk][tx*4];
      float av[4]={a4.x,a4.y,a4.z,a4.w}, bv[4]={b4.x,b4.y,b4.z,b4.w};
      #pragma unroll
      for (int i=0;i<4;++i)
        #pragma unroll
        for (int j=0;j<4;++j) acc[i][j] += av[i]*bv[j];
    }
    __syncthreads();
  }
  int c0 = colBase + tx*4;
  float4 bv4 = *(const float4*)&bias[c0];
  float bb[4]={bv4.x,bv4.y,bv4.z,bv4.w};
  for (int i=0;i<4;++i){
    int r = rowBase + ty*4 + i;
    float o[4];
    #pragma unroll
    for (int j=0;j<4;++j){ float v = acc[i][j] + bb[j]; if (RELU) v = v>0.f?v:0.f; o[j]=v; }
    if (OUTBF){
      unsigned short* Cb = (unsigned short*)C;
      ushort4 p; p.x=f2bf(o[0]); p.y=f2bf(o[1]); p.z=f2bf(o[2]); p.w=f2bf(o[3]);
      *(ushort4*)&Cb[(size_t)r*Nc + c0] = p;
    } else {
      *(float4*)&C[(size_t)r*Nc + c0] = make_float4(o[0],o[1],o[2],o[3]);
    }
  }
}

// ---------------- bf16 MFMA GEMM: C = A@W + bias  (A pre-cast bf16, W pre-transposed bf16) ----------------
// 128x128 tile, 256 thr = 4 waves; wave: 2 row-frags x 8 col-frags of 16x16x32.
__global__ __launch_bounds__(256) void mfma_gemm_bias(
    const unsigned short* __restrict__ Abf, const unsigned short* __restrict__ WT,
    const float* __restrict__ bias, float* __restrict__ C)
{
  __shared__ __align__(16) unsigned short As[128*40];
  __shared__ __align__(16) unsigned short Bs[128*40];
  int tid = threadIdx.x;
  int w = tid >> 6, l = tid & 63;
  int lr = l & 15, lk = (l >> 4) * 8, lq = l >> 4;
  int rowBase = blockIdx.y * 128, colBase = blockIdx.x * 128;
  f4v acc[2][8];
  f4v z = {0.f,0.f,0.f,0.f};
  #pragma unroll
  for (int i=0;i<2;++i)
    #pragma unroll
    for (int j=0;j<8;++j) acc[i][j] = z;

  for (int k0 = 0; k0 < HH; k0 += 32){
    {
      int r = tid >> 1, half = tid & 1;
      const bf16x8* sA = (const bf16x8*)&Abf[(size_t)(rowBase + r)*HH + k0 + half*16];
      bf16x8* dA = (bf16x8*)&As[r*40 + half*16];
      dA[0] = sA[0]; dA[1] = sA[1];
      const bf16x8* sB = (const bf16x8*)&WT[(size_t)(colBase + r)*HH + k0 + half*16];
      bf16x8* dB = (bf16x8*)&Bs[r*40 + half*16];
      dB[0] = sB[0]; dB[1] = sB[1];
    }
    __syncthreads();
    bf16x8 a0 = *(const bf16x8*)&As[(w*32 + lr)*40 + lk];
    bf16x8 a1 = *(const bf16x8*)&As[(w*32 + 16 + lr)*40 + lk];
    #pragma unroll
    for (int fc=0; fc<8; ++fc){
      bf16x8 b = *(const bf16x8*)&Bs[(fc*16 + lr)*40 + lk];
      acc[0][fc] = __builtin_amdgcn_mfma_f32_16x16x32_bf16(a0, b, acc[0][fc], 0,0,0);
      acc[1][fc] = __builtin_amdgcn_mfma_f32_16x16x32_bf16(a1, b, acc[1][fc], 0,0,0);
    }
    __syncthreads();
  }
  #pragma unroll
  for (int fr=0; fr<2; ++fr){
    #pragma unroll
    for (int fc=0; fc<8; ++fc){
      int col = colBase + fc*16 + lr;
      float bv = bias[col];
      #pragma unroll
      for (int r=0;r<4;++r){
        int row = rowBase + w*32 + fr*16 + lq*4 + r;
        C[(size_t)row*H3 + col] = acc[fr][fc][r] + bv;
      }
    }
  }
}

// ---------------- mixed per-step GRU, all-MFMA ----------------
// blocks 0-127: GRU2 (plain bf16 MFMA). blocks 128-255: GRU1 (split hi/lo bf16 MFMA, ~fp32 precision).
// tile per block: 64 rows x (3 gates x 64 h-cols). fp32 gate epilogue.
__global__ __launch_bounds__(256) void gru_step_mix2(
    const float* __restrict__ hp1, const float* __restrict__ hp2,
    const float* __restrict__ gi1, const float* __restrict__ gi2,
    const unsigned short* __restrict__ Wh1TH, const unsigned short* __restrict__ Wh1TL,
    const unsigned short* __restrict__ Wh2T,
    const float* __restrict__ bhn1, const float* __restrict__ bhn2,
    const float* __restrict__ mask_t,
    float* __restrict__ ho1, float* __restrict__ ho2)
{
  __shared__ __align__(16) char smem[40960];
  int bid = blockIdx.x;
  int tid = threadIdx.x;
  int w = tid >> 6, l = tid & 63;
  int lr = l & 15, lk = (l >> 4) * 8, lq = l >> 4;

  if (bid < 128){
    // ===== GRU2: plain bf16 MFMA (validated round 8) =====
    unsigned short* As = (unsigned short*)smem;            // [64][40]
    unsigned short* Bs = (unsigned short*)smem + 64*40;    // [192][40]
    int ct = bid & 7, rt = bid >> 3;
    int rowBase = rt << 6, colBase = ct << 6;
    f4v acc[12];
    f4v z = {0.f,0.f,0.f,0.f};
    #pragma unroll
    for (int i=0;i<12;++i) acc[i] = z;

    for (int k0 = 0; k0 < HH; k0 += 32){
      {
        int r = tid >> 2, grp = tid & 3;
        float m = mask_t[rowBase + r];
        const float4* s = (const float4*)&hp2[(size_t)(rowBase + r)*HH + k0 + grp*8];
        float4 v0 = s[0], v1 = s[1];
        union { unsigned short u[8]; uint4 v; } p;
        p.u[0]=f2bf(v0.x*m); p.u[1]=f2bf(v0.y*m); p.u[2]=f2bf(v0.z*m); p.u[3]=f2bf(v0.w*m);
        p.u[4]=f2bf(v1.x*m); p.u[5]=f2bf(v1.y*m); p.u[6]=f2bf(v1.z*m); p.u[7]=f2bf(v1.w*m);
        *(uint4*)&As[r*40 + grp*8] = p.v;
      }
      #pragma unroll
      for (int i=0;i<3;++i){
        int unit = i*256 + tid;          // 768 x 16B
        int brow = unit >> 2, q = unit & 3;
        int g = brow >> 6, c = brow & 63;
        *(bf16x8*)&Bs[brow*40 + q*8] =
            *(const bf16x8*)&Wh2T[(size_t)(g*HH + colBase + c)*HH + k0 + q*8];
      }
      __syncthreads();
      bf16x8 a = *(const bf16x8*)&As[(w*16 + lr)*40 + lk];
      #pragma unroll
      for (int cf=0; cf<12; ++cf){
        bf16x8 b = *(const bf16x8*)&Bs[(cf*16 + lr)*40 + lk];
        acc[cf] = __builtin_amdgcn_mfma_f32_16x16x32_bf16(a, b, acc[cf], 0,0,0);
      }
      __syncthreads();
    }
    #pragma unroll
    for (int f=0; f<4; ++f){
      int hcol = colBase + f*16 + lr;
      float bn = bhn2[hcol];
      #pragma unroll
      for (int r=0;r<4;++r){
        int row = rowBase + w*16 + lq*4 + r;
        size_t gb = (size_t)row*H3 + hcol;
        float g_r = __builtin_nontemporal_load(&gi2[gb]);
        float g_z = __builtin_nontemporal_load(&gi2[gb + HH]);
        float g_n = __builtin_nontemporal_load(&gi2[gb + 2*HH]);
        float hv  = hp2[(size_t)row*HH + hcol] * mask_t[row];
        float rg = sigm(g_r + acc[f][r]);
        float zg = sigm(g_z + acc[4+f][r]);
        float ng = tanhf(g_n + rg*(acc[8+f][r] + bn));
        ho2[(size_t)row*HH + hcol] = (1.f - zg)*ng + zg*hv;
      }
    }
  } else {
    // ===== GRU1: split hi/lo bf16 MFMA (~fp32 precision: err ~2^-17 per term) =====
    unsigned short* AsH = (unsigned short*)smem;             // [64][40]
    unsigned short* AsL = AsH + 64*40;
    unsigned short* BsH = AsL + 64*40;                       // [192][40]
    unsigned short* BsL = BsH + 192*40;
    int bidp = bid - 128;
    int ct = bidp & 7, rt = bidp >> 3;
    int rowBase = rt << 6, colBase = ct << 6;
    f4v acc[12];
    f4v z = {0.f,0.f,0.f,0.f};
    #pragma unroll
    for (int i=0;i<12;++i) acc[i] = z;

    for (int k0 = 0; k0 < HH; k0 += 32){
      // stage A hi/lo: 64 rows x 32 k of masked h1
      {
        int r = tid >> 2, grp = tid & 3;
        float m = mask_t[rowBase + r];
        const float4* s = (const float4*)&hp1[(size_t)(rowBase + r)*HH + k0 + grp*8];
        float4 v0 = s[0], v1 = s[1];
        float x[8] = {v0.x*m, v0.y*m, v0.z*m, v0.w*m, v1.x*m, v1.y*m, v1.z*m, v1.w*m};
        union { unsigned short u[8]; uint4 v; } ph, pl;
        #pragma unroll
        for (int j=0;j<8;++j){
          unsigned short hi = f2bf(x[j]);
          ph.u[j] = hi;
          pl.u[j] = f2bf(x[j] - bf2f(hi));
        }
        *(uint4*)&AsH[r*40 + grp*8] = ph.v;
        *(uint4*)&AsL[r*40 + grp*8] = pl.v;
      }
      // stage B hi/lo
      #pragma unroll
      for (int i=0;i<3;++i){
        int unit = i*256 + tid;
        int brow = unit >> 2, q = unit & 3;
        int g = brow >> 6, c = brow & 63;
        size_t src = (size_t)(g*HH + colBase + c)*HH + k0 + q*8;
        *(bf16x8*)&BsH[brow*40 + q*8] = *(const bf16x8*)&Wh1TH[src];
        *(bf16x8*)&BsL[brow*40 + q*8] = *(const bf16x8*)&Wh1TL[src];
      }
      __syncthreads();
      bf16x8 aH = *(const bf16x8*)&AsH[(w*16 + lr)*40 + lk];
      bf16x8 aL = *(const bf16x8*)&AsL[(w*16 + lr)*40 + lk];
      #pragma unroll
      for (int cf=0; cf<12; ++cf){
        bf16x8 bH = *(const bf16x8*)&BsH[(cf*16 + lr)*40 + lk];
        bf16x8 bL = *(const bf16x8*)&BsL[(cf*16 + lr)*40 + lk];
        acc[cf] = __builtin_amdgcn_mfma_f32_16x16x32_bf16(aH, bH, acc[cf], 0,0,0);
        acc[cf] = __builtin_amdgcn_mfma_f32_16x16x32_bf16(aH, bL, acc[cf], 0,0,0);
        acc[cf] = __builtin_amdgcn_mfma_f32_16x16x32_bf16(aL, bH, acc[cf], 0,0,0);
      }
      __syncthreads();
    }
    #pragma unroll
    for (int f=0; f<4; ++f){
      int hcol = colBase + f*16 + lr;
      float bn = bhn1[hcol];
      #pragma unroll
      for (int r=0;r<4;++r){
        int row = rowBase + w*16 + lq*4 + r;
        size_t gb = (size_t)row*H3 + hcol;
        float g_r = __builtin_nontemporal_load(&gi1[gb]);
        float g_z = __builtin_nontemporal_load(&gi1[gb + HH]);
        float g_n = __builtin_nontemporal_load(&gi1[gb + 2*HH]);
        float hv  = hp1[(size_t)row*HH + hcol] * mask_t[row];
        float rg = sigm(g_r + acc[f][r]);
        float zg = sigm(g_z + acc[4+f][r]);
        float ng = tanhf(g_n + rg*(acc[8+f][r] + bn));
        ho1[(size_t)row*HH + hcol] = (1.f - zg)*ng + zg*hv;
      }
    }
  }
}

// ---------------- logits + first-max argmax (chunked: t = t0 + local) ----------------
__global__ __launch_bounds__(256) void k_logits(const float* __restrict__ ae2,
    const float* __restrict__ e, float* __restrict__ out_logits, int* __restrict__ argk, int t0)
{
  __shared__ float es[KK*SS];
  int tid = threadIdx.x;
  for (int i=0;i<4;++i) es[tid + i*256] = e[tid + i*256];
  __syncthreads();
  int g = blockIdx.x*256 + tid;
  int t = t0 + (g >> 10), j = g & 1023;
  const float* arow = &ae2[(size_t)g * SS];
  float a[SS];
  #pragma unroll
  for (int i=0;i<16;++i){ float4 v = ((const float4*)arow)[i]; a[4*i]=v.x; a[4*i+1]=v.y; a[4*i+2]=v.z; a[4*i+3]=v.w; }
  float lg[KK];
  float best = -INFINITY; int bk = 0;
  for (int k=0;k<KK;++k){
    float s2 = 0.f;
    #pragma unroll 8
    for (int s=0;s<SS;++s) s2 += a[s]*es[k*SS+s];
    lg[k] = s2;
    if (s2 > best){ best = s2; bk = k; }
  }
  int n = j >> 7, b = j & 127;
  size_t ob = ((size_t)((t*BB + b)*NN + n)) * KK;
  #pragma unroll
  for (int k4=0;k4<4;++k4)
    *(float4*)&out_logits[ob + k4*4] = make_float4(lg[k4*4],lg[k4*4+1],lg[k4*4+2],lg[k4*4+3]);
  argk[(t*BB + b)*NN + n] = bk;   // (b,n)-major: matches reference's prob/q index quirk
}

// ---------------- q selection (chunked) ----------------
__global__ __launch_bounds__(64) void k_qsel(const float* __restrict__ y2,
    const float* __restrict__ w1, const float* __restrict__ b1,
    const int* __restrict__ argk, float* __restrict__ outq)
{
  __shared__ float yr[HH];
  __shared__ float part[64];
  int bj = blockIdx.x;
  int tid = threadIdx.x;
  const float4* row4 = (const float4*)&y2[(size_t)bj*HH];
  ((float4*)yr)[tid]    = row4[tid];
  ((float4*)yr)[tid+64] = row4[tid+64];
  __syncthreads();
  int k = argk[bj];
  int a = tid & 15, q4 = tid >> 4;
  const float* wp = &w1[(size_t)k*HH*AA + a];
  float s = 0.f;
  int h0 = q4*128;
  #pragma unroll 8
  for (int h=h0; h<h0+128; ++h) s += yr[h]*wp[(size_t)h*AA];
  part[tid] = s;
  __syncthreads();
  if (q4 == 0){
    float v = part[a] + part[a+16] + part[a+32] + part[a+48] + b1[k*AA + a];
    outq[(size_t)bj*AA + a] = v;
  }
}

// ---------------- orchestration ----------------
extern "C" void kernel_launch(void* const* d_in, const int* in_sizes, int n_in,
                              void* d_out, int out_size, void* d_ws, size_t ws_size,
                              hipStream_t stream)
{
  (void)in_sizes; (void)n_in; (void)out_size;
  const float* h1     = (const float*)d_in[0];
  const float* h2     = (const float*)d_in[1];
  const float* obs    = (const float*)d_in[2];
  const unsigned char* done_raw = (const unsigned char*)d_in[3];
  const float* W_embed=(const float*)d_in[4];  const float* b_embed=(const float*)d_in[5];
  const float* Wi1    =(const float*)d_in[6];  const float* bi1    =(const float*)d_in[7];
  const float* Wh1    =(const float*)d_in[8];  const float* bhn1   =(const float*)d_in[9];
  const float* W_sub  =(const float*)d_in[10]; const float* b_sub  =(const float*)d_in[11];
  const float* W_e1   =(const float*)d_in[12]; const float* b_e1   =(const float*)d_in[13];
  const float* W_e2   =(const float*)d_in[14]; const float* b_e2   =(const float*)d_in[15];
  const float* W_pol  =(const float*)d_in[16]; const float* b_pol  =(const float*)d_in[17];
  const float* Wi2    =(const float*)d_in[18]; const float* bi2    =(const float*)d_in[19];
  const float* Wh2    =(const float*)d_in[20]; const float* bhn2   =(const float*)d_in[21];
  const float* W_w1   =(const float*)d_in[22]; const float* b_w1   =(const float*)d_in[23];
  const float* W_b1   =(const float*)d_in[24]; const float* b_b1   =(const float*)d_in[25];

  float* out    = (float*)d_out;
  float* outHT1 = out;
  float* outHT2 = out + (size_t)NB*HH;
  float* outQ   = out + 2ull*NB*HH;
  float* outLG  = outQ + (size_t)TT*NB*AA;
  float* outSE  = outLG + (size_t)TT*BB*NN*KK;

  // ---- adaptive chunk size from ws_size (float units; includes bf16 buffers) ----
  const size_t fixed_f = 2ull*NB*HH + (size_t)TT*NB + 1024
                       + (size_t)KK*HH*AA + 256 + (size_t)TT*NB + 64
                       + 2ull*H3*HH/2                    // Wi2T + Wh2T (bf16)
                       + (size_t)H3*HH;                  // Wh1T hi+lo (bf16)
  const size_t per_t_f = (size_t)NB*(2*HH + 2*H3 + SS) + (size_t)NB*HH/2;  // + buf2bf
  int CH = 64;
  while (CH > 1 && (fixed_f + per_t_f*(size_t)CH)*4 > ws_size) CH >>= 1;

  float* buf1   = (float*)d_ws;                        // ae1/y1 chunk: CH*NB*HH
  float* buf2   = buf1   + (size_t)CH*NB*HH;           // y2 chunk
  float* gbuf1  = buf2   + (size_t)CH*NB*HH;           // gi1 chunk: CH*NB*H3
  float* gbuf2  = gbuf1  + (size_t)CH*NB*H3;           // gi2 chunk
  float* ae2buf = gbuf2  + (size_t)CH*NB*H3;           // CH*NB*SS
  float* h_last1= ae2buf + (size_t)CH*NB*SS;
  float* h_last2= h_last1+ (size_t)NB*HH;
  float* maskp  = h_last2+ (size_t)NB*HH;
  float* ws_e   = maskp  + (size_t)TT*NB;
  float* ws_w1  = ws_e   + 1024;
  float* ws_b1  = ws_w1  + (size_t)KK*HH*AA;
  int*   ws_argk= (int*)(ws_b1 + 256);
  int*   ws_flag= (int*)(ws_argk + (size_t)TT*NB);
  unsigned short* buf2bf = (unsigned short*)(ws_flag + 64);   // CH*NB*HH bf16 (sp)
  unsigned short* wi2t   = buf2bf + (size_t)CH*NB*HH;         // 1536*512 bf16
  unsigned short* wh2t   = wi2t   + (size_t)H3*HH;            // 1536*512 bf16
  unsigned short* wh1th  = wh2t   + (size_t)H3*HH;            // 1536*512 bf16
  unsigned short* wh1tl  = wh1th  + (size_t)H3*HH;            // 1536*512 bf16

  // phase 0
  k_detect<<<1,256,0,stream>>>(done_raw, ws_flag);
  k_mask<<<TT*NB/256,256,0,stream>>>(done_raw, ws_flag, maskp);
  k_e<<<1,256,0,stream>>>(W_e1,b_e1,W_e2,b_e2,ws_e);
  k_w1b1<<<128,256,0,stream>>>(ws_e,W_w1,b_w1,W_b1,b_b1,ws_w1,ws_b1);
  k_se<<<2048,256,0,stream>>>(ws_e,outSE);
  k_transpose_bf16<<<dim3(48,16),256,0,stream>>>(Wi2, wi2t);
  k_transpose_bf16<<<dim3(48,16),256,0,stream>>>(Wh2, wh2t);
  k_transpose_split<<<dim3(48,16),256,0,stream>>>(Wh1, wh1th, wh1tl);
  k_copy<<<512,256,0,stream>>>(h1, h_last1, NB*HH/4);
  k_copy<<<512,256,0,stream>>>(h2, h_last2, NB*HH/4);

  dim3 thr(256);
  const int NCH = TT / CH;
  for (int c = 0; c < NCH; ++c){
    int t0 = c * CH;
    const float* obs_c = obs + (size_t)t0*NB*DD;
    // branch-1 front (exact fp32)
    gemm_bias_act<1,0><<<dim3(HH/64, CH*NB/64),thr,0,stream>>>(obs_c, W_embed, b_embed, buf1, CH*NB, DD, HH);
    gemm_bias_act<0,0><<<dim3(H3/64, CH*NB/64),thr,0,stream>>>(buf1, Wi1, bi1, gbuf1, CH*NB, HH, H3);
    // branch-2 front: embed writes bf16 directly, gi2 via MFMA
    gemm_bias_act<1,1><<<dim3(HH/64, CH*NB/64),thr,0,stream>>>(obs_c, W_pol, b_pol, (float*)buf2bf, CH*NB, DD, HH);
    mfma_gemm_bias<<<dim3(H3/128, CH*NB/128),thr,0,stream>>>(buf2bf, wi2t, bi2, gbuf2);
    // dual-GRU scan: all-MFMA per-step launch (GRU1 split hi/lo, GRU2 plain bf16)
    for (int lt = 0; lt < CH; ++lt){
      const float* hp1 = (lt == 0) ? h_last1 : (buf1 + (size_t)(lt-1)*NB*HH);
      const float* hp2 = (lt == 0) ? h_last2 : (buf2 + (size_t)(lt-1)*NB*HH);
      gru_step_mix2<<<256, 256, 0, stream>>>(hp1, hp2,
                                             gbuf1 + (size_t)lt*NB*H3, gbuf2 + (size_t)lt*NB*H3,
                                             wh1th, wh1tl, wh2t, bhn1, bhn2,
                                             maskp + (size_t)(t0+lt)*NB,
                                             buf1 + (size_t)lt*NB*HH, buf2 + (size_t)lt*NB*HH);
    }
    k_copy<<<512,256,0,stream>>>(buf1 + (size_t)(CH-1)*NB*HH, h_last1, NB*HH/4);
    k_copy<<<512,256,0,stream>>>(buf2 + (size_t)(CH-1)*NB*HH, h_last2, NB*HH/4);
    // tails
    gemm_bias_act<0,0><<<dim3(SS/64, CH*NB/64),thr,0,stream>>>(buf1, W_sub, b_sub, ae2buf, CH*NB, HH, SS);
    k_logits<<<CH*NB/256,256,0,stream>>>(ae2buf, ws_e, outLG, ws_argk, t0);
    k_qsel<<<CH*NB,64,0,stream>>>(buf2, ws_w1, ws_b1, ws_argk + (size_t)t0*NB, outQ + (size_t)t0*NB*AA);
  }
  k_copy<<<512,256,0,stream>>>(h_last1, outHT1, NB*HH/4);
  k_copy<<<512,256,0,stream>>>(h_last2, outHT2, NB*HH/4);
}

// Round 10
// 4693.265 us; speedup vs baseline: 5.1176x; 1.2297x over previous
//
#include <hip/hip_runtime.h>
#include <hip/hip_bf16.h>
#include <math.h>

#define TT 64
#define NN 8
#define BB 128
#define DD 128
#define HH 512
#define SS 64
#define KK 16
#define AA 16
#define NB 1024
#define H3 (3*HH)       /* 1536 */

typedef float f4v __attribute__((ext_vector_type(4)));
typedef short bf16x8 __attribute__((ext_vector_type(8)));

__device__ __forceinline__ float sigm(float x){ return 1.0f/(1.0f+expf(-x)); }
__device__ __forceinline__ unsigned short f2bf(float f){
  unsigned u = __float_as_uint(f);
  u += 0x7FFF + ((u >> 16) & 1);          // round-to-nearest-even
  return (unsigned short)(u >> 16);
}
__device__ __forceinline__ float bf2f(unsigned short h){
  return __uint_as_float(((unsigned)h) << 16);
}

// ---------------- done-layout detection + mask expansion ----------------
__global__ __launch_bounds__(256) void k_detect(const unsigned char* __restrict__ raw,
                                                int* __restrict__ flag)
{
  __shared__ int cA, cB;
  if (threadIdx.x == 0){ cA = 0; cB = 0; }
  __syncthreads();
  int a = 0, b = 0;
  for (int i = threadIdx.x; i < TT*NB; i += 256){
    unsigned char v = raw[i];
    if (v > 1) a++;
    if ((i & 3) != 0 && v != 0) b++;
  }
  atomicAdd(&cA, a); atomicAdd(&cB, b);
  __syncthreads();
  if (threadIdx.x == 0) *flag = (cB == 0) ? 0 : (cA == 0 ? 1 : 2);
}

__global__ __launch_bounds__(256) void k_mask(const unsigned char* __restrict__ raw,
                                              const int* __restrict__ flag,
                                              float* __restrict__ mask)
{
  int i = blockIdx.x*256 + threadIdx.x;
  if (i >= TT*NB) return;
  int f = *flag;
  int v;
  if (f == 1)      v = (int)raw[i];
  else if (f == 0) v = ((const int*)raw)[i];
  else             v = (((const float*)raw)[i] != 0.0f);
  mask[i] = v ? 0.f : 1.f;   // 0 => reset carry
}

// ---------------- small setup kernels ----------------

__global__ __launch_bounds__(256) void k_e(const float* __restrict__ W_e1, const float* __restrict__ b_e1,
                                           const float* __restrict__ W_e2, const float* __restrict__ b_e2,
                                           float* __restrict__ e_out)
{
  __shared__ float r1[KK*SS];
  int tid = threadIdx.x;
  for (int i=0;i<4;++i){ int l = tid + i*256; float v = W_e1[l] + b_e1[l & 63]; r1[l] = v > 0.f ? v : 0.f; }
  __syncthreads();
  for (int i=0;i<4;++i){
    int l = tid + i*256; int k = l >> 6, s = l & 63;
    float acc = b_e2[s];
    #pragma unroll 8
    for (int sp=0; sp<64; ++sp) acc += r1[k*64+sp] * W_e2[sp*64 + s];
    e_out[l] = tanhf(acc);
  }
}

__global__ __launch_bounds__(256) void k_w1b1(const float* __restrict__ e, const float* __restrict__ W_w1,
                                              const float* __restrict__ b_w1, const float* __restrict__ W_b1,
                                              const float* __restrict__ b_b1, float* __restrict__ w1,
                                              float* __restrict__ b1)
{
  __shared__ float es[KK*SS];
  int tid = threadIdx.x;
  for (int i=0;i<4;++i) es[tid + i*256] = e[tid + i*256];
  __syncthreads();
  for (int i=0;i<4;++i){
    int l = blockIdx.x*1024 + tid + i*256;
    int k = l >> 13, m = l & 8191;
    float acc = b_w1[m];
    #pragma unroll 8
    for (int s=0;s<64;++s) acc += es[k*64+s] * W_w1[(size_t)s*8192 + m];
    w1[l] = acc;
  }
  if (blockIdx.x == 0){
    int k = tid >> 4, a = tid & 15;
    float acc = b_b1[a];
    #pragma unroll 8
    for (int s=0;s<64;++s) acc += es[k*64+s] * W_b1[s*16 + a];
    b1[tid] = acc;
  }
}

__global__ __launch_bounds__(256) void k_se(const float* __restrict__ e, float* __restrict__ outse)
{
  __shared__ float4 es[256];
  es[threadIdx.x] = ((const float4*)e)[threadIdx.x];
  __syncthreads();
  const int total4 = TT*BB*KK*SS/4;
  for (int i = blockIdx.x*256 + threadIdx.x; i < total4; i += gridDim.x*256)
    ((float4*)outse)[i] = es[i & 255];
}

__global__ void k_copy(const float* __restrict__ src, float* __restrict__ dst, int n4)
{
  int i = blockIdx.x*blockDim.x + threadIdx.x;
  if (i < n4) ((float4*)dst)[i] = ((const float4*)src)[i];
}

// generic transpose + split: W [Kd][Nc] f32 -> WTh/WTl [Nc][Kd] bf16
__global__ __launch_bounds__(256) void k_tsplit(const float* __restrict__ W,
                                                unsigned short* __restrict__ WTh,
                                                unsigned short* __restrict__ WTl,
                                                int Kd, int Nc)
{
  __shared__ float t[32][33];
  int n0 = blockIdx.x * 32;
  int k0 = blockIdx.y * 32;
  int c = threadIdx.x & 31, r8 = threadIdx.x >> 5;
  for (int i=0;i<4;++i){
    int r = r8 + i*8;
    t[r][c] = W[(size_t)(k0+r)*Nc + n0 + c];
  }
  __syncthreads();
  for (int i=0;i<4;++i){
    int nr = r8 + i*8;
    float v = t[c][nr];
    unsigned short hi = f2bf(v);
    WTh[(size_t)(n0+nr)*Kd + k0 + c] = hi;
    WTl[(size_t)(n0+nr)*Kd + k0 + c] = f2bf(v - bf2f(hi));
  }
}

// f32 -> (hi, lo) bf16 flat split-cast, 8 elems/thread
__global__ void k_split_cast(const float* __restrict__ src,
                             unsigned short* __restrict__ dh,
                             unsigned short* __restrict__ dl, int n8)
{
  int i = blockIdx.x*blockDim.x + threadIdx.x;
  if (i >= n8) return;
  const float4* s = (const float4*)(src + (size_t)i*8);
  float4 a = s[0], b = s[1];
  float x[8] = {a.x,a.y,a.z,a.w,b.x,b.y,b.z,b.w};
  union { unsigned short u[8]; uint4 v; } ph, pl;
  #pragma unroll
  for (int j=0;j<8;++j){
    unsigned short hi = f2bf(x[j]);
    ph.u[j] = hi;
    pl.u[j] = f2bf(x[j] - bf2f(hi));
  }
  *(uint4*)&dh[(size_t)i*8] = ph.v;
  *(uint4*)&dl[(size_t)i*8] = pl.v;
}

// ---------------- unified MFMA GEMM ----------------
// C = act(A@B^T + bias). A: [M][KD] bf16 (hi/lo if SPLIT), B: WT [N][KD] bf16 (hi/lo if SPLIT).
// Tile 128 rows x NTILE cols, 256 thr = 4 waves; wave: 2 row-frags x NTILE/16 col-frags.
// OUTMODE: 0 = fp32 C, 1 = bf16 Chi, 2 = split pair (Chi, Clo).
template<int KD, int SPLIT, int NTILE, int RELU, int OUTMODE>
__global__ __launch_bounds__(256) void mfma_gemm(
    const unsigned short* Ah, const unsigned short* Al,
    const unsigned short* Bh, const unsigned short* Bl,
    const float* __restrict__ bias,
    float* C, unsigned short* Chi, unsigned short* Clo, int Nstride)
{
  constexpr int NFC = NTILE/16;
  __shared__ __align__(16) unsigned short AsH[128*40];
  __shared__ __align__(16) unsigned short BsH[NTILE*40];
  __shared__ __align__(16) unsigned short AsL[SPLIT ? 128*40 : 8];
  __shared__ __align__(16) unsigned short BsL[SPLIT ? NTILE*40 : 8];
  int tid = threadIdx.x;
  int w = tid >> 6, l = tid & 63;
  int lr = l & 15, lk = (l >> 4) * 8, lq = l >> 4;
  int rowBase = blockIdx.y * 128, colBase = blockIdx.x * NTILE;
  f4v acc[2][NFC];
  f4v z = {0.f,0.f,0.f,0.f};
  #pragma unroll
  for (int i=0;i<2;++i)
    #pragma unroll
    for (int j=0;j<NFC;++j) acc[i][j] = z;

  for (int k0 = 0; k0 < KD; k0 += 32){
    // stage A: 128 rows x 32 k
    {
      int r = tid >> 1, half = tid & 1;
      size_t src = (size_t)(rowBase + r)*KD + k0 + half*16;
      bf16x8* dA = (bf16x8*)&AsH[r*40 + half*16];
      dA[0] = *(const bf16x8*)&Ah[src];
      dA[1] = *(const bf16x8*)&Ah[src + 8];
      if (SPLIT){
        bf16x8* dL = (bf16x8*)&AsL[r*40 + half*16];
        dL[0] = *(const bf16x8*)&Al[src];
        dL[1] = *(const bf16x8*)&Al[src + 8];
      }
    }
    // stage B: NTILE rows x 32 k
    if (NTILE == 128){
      int r = tid >> 1, half = tid & 1;
      size_t src = (size_t)(colBase + r)*KD + k0 + half*16;
      bf16x8* dB = (bf16x8*)&BsH[r*40 + half*16];
      dB[0] = *(const bf16x8*)&Bh[src];
      dB[1] = *(const bf16x8*)&Bh[src + 8];
      if (SPLIT){
        bf16x8* dL = (bf16x8*)&BsL[r*40 + half*16];
        dL[0] = *(const bf16x8*)&Bl[src];
        dL[1] = *(const bf16x8*)&Bl[src + 8];
      }
    } else {   // NTILE == 64
      int r = tid >> 2, q = tid & 3;
      size_t src = (size_t)(colBase + r)*KD + k0 + q*8;
      *(bf16x8*)&BsH[r*40 + q*8] = *(const bf16x8*)&Bh[src];
      if (SPLIT)
        *(bf16x8*)&BsL[r*40 + q*8] = *(const bf16x8*)&Bl[src];
    }
    __syncthreads();
    bf16x8 aH0 = *(const bf16x8*)&AsH[(w*32 + lr)*40 + lk];
    bf16x8 aH1 = *(const bf16x8*)&AsH[(w*32 + 16 + lr)*40 + lk];
    bf16x8 aL0, aL1;
    if (SPLIT){
      aL0 = *(const bf16x8*)&AsL[(w*32 + lr)*40 + lk];
      aL1 = *(const bf16x8*)&AsL[(w*32 + 16 + lr)*40 + lk];
    }
    #pragma unroll
    for (int fc=0; fc<NFC; ++fc){
      bf16x8 bH = *(const bf16x8*)&BsH[(fc*16 + lr)*40 + lk];
      acc[0][fc] = __builtin_amdgcn_mfma_f32_16x16x32_bf16(aH0, bH, acc[0][fc], 0,0,0);
      acc[1][fc] = __builtin_amdgcn_mfma_f32_16x16x32_bf16(aH1, bH, acc[1][fc], 0,0,0);
      if (SPLIT){
        bf16x8 bL = *(const bf16x8*)&BsL[(fc*16 + lr)*40 + lk];
        acc[0][fc] = __builtin_amdgcn_mfma_f32_16x16x32_bf16(aH0, bL, acc[0][fc], 0,0,0);
        acc[1][fc] = __builtin_amdgcn_mfma_f32_16x16x32_bf16(aH1, bL, acc[1][fc], 0,0,0);
        acc[0][fc] = __builtin_amdgcn_mfma_f32_16x16x32_bf16(aL0, bH, acc[0][fc], 0,0,0);
        acc[1][fc] = __builtin_amdgcn_mfma_f32_16x16x32_bf16(aL1, bH, acc[1][fc], 0,0,0);
      }
    }
    __syncthreads();
  }
  #pragma unroll
  for (int fr=0; fr<2; ++fr){
    #pragma unroll
    for (int fc=0; fc<NFC; ++fc){
      int col = colBase + fc*16 + lr;
      float bv = bias[col];
      #pragma unroll
      for (int r=0;r<4;++r){
        int row = rowBase + w*32 + fr*16 + lq*4 + r;
        float v = acc[fr][fc][r] + bv;
        if (RELU) v = v > 0.f ? v : 0.f;
        size_t o = (size_t)row*Nstride + col;
        if (OUTMODE == 0) C[o] = v;
        else if (OUTMODE == 1) Chi[o] = f2bf(v);
        else {
          unsigned short hi = f2bf(v);
          Chi[o] = hi;
          Clo[o] = f2bf(v - bf2f(hi));
        }
      }
    }
  }
}

// ---------------- mixed per-step GRU, all-MFMA (validated round 9) ----------------
__global__ __launch_bounds__(256) void gru_step_mix2(
    const float* __restrict__ hp1, const float* __restrict__ hp2,
    const float* __restrict__ gi1, const float* __restrict__ gi2,
    const unsigned short* __restrict__ Wh1TH, const unsigned short* __restrict__ Wh1TL,
    const unsigned short* __restrict__ Wh2T,
    const float* __restrict__ bhn1, const float* __restrict__ bhn2,
    const float* __restrict__ mask_t,
    float* __restrict__ ho1, float* __restrict__ ho2)
{
  __shared__ __align__(16) char smem[40960];
  int bid = blockIdx.x;
  int tid = threadIdx.x;
  int w = tid >> 6, l = tid & 63;
  int lr = l & 15, lk = (l >> 4) * 8, lq = l >> 4;

  if (bid < 128){
    // ===== GRU2: plain bf16 MFMA =====
    unsigned short* As = (unsigned short*)smem;            // [64][40]
    unsigned short* Bs = (unsigned short*)smem + 64*40;    // [192][40]
    int ct = bid & 7, rt = bid >> 3;
    int rowBase = rt << 6, colBase = ct << 6;
    f4v acc[12];
    f4v z = {0.f,0.f,0.f,0.f};
    #pragma unroll
    for (int i=0;i<12;++i) acc[i] = z;

    for (int k0 = 0; k0 < HH; k0 += 32){
      {
        int r = tid >> 2, grp = tid & 3;
        float m = mask_t[rowBase + r];
        const float4* s = (const float4*)&hp2[(size_t)(rowBase + r)*HH + k0 + grp*8];
        float4 v0 = s[0], v1 = s[1];
        union { unsigned short u[8]; uint4 v; } p;
        p.u[0]=f2bf(v0.x*m); p.u[1]=f2bf(v0.y*m); p.u[2]=f2bf(v0.z*m); p.u[3]=f2bf(v0.w*m);
        p.u[4]=f2bf(v1.x*m); p.u[5]=f2bf(v1.y*m); p.u[6]=f2bf(v1.z*m); p.u[7]=f2bf(v1.w*m);
        *(uint4*)&As[r*40 + grp*8] = p.v;
      }
      #pragma unroll
      for (int i=0;i<3;++i){
        int unit = i*256 + tid;          // 768 x 16B
        int brow = unit >> 2, q = unit & 3;
        int g = brow >> 6, c = brow & 63;
        *(bf16x8*)&Bs[brow*40 + q*8] =
            *(const bf16x8*)&Wh2T[(size_t)(g*HH + colBase + c)*HH + k0 + q*8];
      }
      __syncthreads();
      bf16x8 a = *(const bf16x8*)&As[(w*16 + lr)*40 + lk];
      #pragma unroll
      for (int cf=0; cf<12; ++cf){
        bf16x8 b = *(const bf16x8*)&Bs[(cf*16 + lr)*40 + lk];
        acc[cf] = __builtin_amdgcn_mfma_f32_16x16x32_bf16(a, b, acc[cf], 0,0,0);
      }
      __syncthreads();
    }
    #pragma unroll
    for (int f=0; f<4; ++f){
      int hcol = colBase + f*16 + lr;
      float bn = bhn2[hcol];
      #pragma unroll
      for (int r=0;r<4;++r){
        int row = rowBase + w*16 + lq*4 + r;
        size_t gb = (size_t)row*H3 + hcol;
        float g_r = __builtin_nontemporal_load(&gi2[gb]);
        float g_z = __builtin_nontemporal_load(&gi2[gb + HH]);
        float g_n = __builtin_nontemporal_load(&gi2[gb + 2*HH]);
        float hv  = hp2[(size_t)row*HH + hcol] * mask_t[row];
        float rg = sigm(g_r + acc[f][r]);
        float zg = sigm(g_z + acc[4+f][r]);
        float ng = tanhf(g_n + rg*(acc[8+f][r] + bn));
        ho2[(size_t)row*HH + hcol] = (1.f - zg)*ng + zg*hv;
      }
    }
  } else {
    // ===== GRU1: split hi/lo bf16 MFMA (~fp32 precision) =====
    unsigned short* AsH = (unsigned short*)smem;             // [64][40]
    unsigned short* AsL = AsH + 64*40;
    unsigned short* BsH = AsL + 64*40;                       // [192][40]
    unsigned short* BsL = BsH + 192*40;
    int bidp = bid - 128;
    int ct = bidp & 7, rt = bidp >> 3;
    int rowBase = rt << 6, colBase = ct << 6;
    f4v acc[12];
    f4v z = {0.f,0.f,0.f,0.f};
    #pragma unroll
    for (int i=0;i<12;++i) acc[i] = z;

    for (int k0 = 0; k0 < HH; k0 += 32){
      {
        int r = tid >> 2, grp = tid & 3;
        float m = mask_t[rowBase + r];
        const float4* s = (const float4*)&hp1[(size_t)(rowBase + r)*HH + k0 + grp*8];
        float4 v0 = s[0], v1 = s[1];
        float x[8] = {v0.x*m, v0.y*m, v0.z*m, v0.w*m, v1.x*m, v1.y*m, v1.z*m, v1.w*m};
        union { unsigned short u[8]; uint4 v; } ph, pl;
        #pragma unroll
        for (int j=0;j<8;++j){
          unsigned short hi = f2bf(x[j]);
          ph.u[j] = hi;
          pl.u[j] = f2bf(x[j] - bf2f(hi));
        }
        *(uint4*)&AsH[r*40 + grp*8] = ph.v;
        *(uint4*)&AsL[r*40 + grp*8] = pl.v;
      }
      #pragma unroll
      for (int i=0;i<3;++i){
        int unit = i*256 + tid;
        int brow = unit >> 2, q = unit & 3;
        int g = brow >> 6, c = brow & 63;
        size_t src = (size_t)(g*HH + colBase + c)*HH + k0 + q*8;
        *(bf16x8*)&BsH[brow*40 + q*8] = *(const bf16x8*)&Wh1TH[src];
        *(bf16x8*)&BsL[brow*40 + q*8] = *(const bf16x8*)&Wh1TL[src];
      }
      __syncthreads();
      bf16x8 aH = *(const bf16x8*)&AsH[(w*16 + lr)*40 + lk];
      bf16x8 aL = *(const bf16x8*)&AsL[(w*16 + lr)*40 + lk];
      #pragma unroll
      for (int cf=0; cf<12; ++cf){
        bf16x8 bH = *(const bf16x8*)&BsH[(cf*16 + lr)*40 + lk];
        bf16x8 bL = *(const bf16x8*)&BsL[(cf*16 + lr)*40 + lk];
        acc[cf] = __builtin_amdgcn_mfma_f32_16x16x32_bf16(aH, bH, acc[cf], 0,0,0);
        acc[cf] = __builtin_amdgcn_mfma_f32_16x16x32_bf16(aH, bL, acc[cf], 0,0,0);
        acc[cf] = __builtin_amdgcn_mfma_f32_16x16x32_bf16(aL, bH, acc[cf], 0,0,0);
      }
      __syncthreads();
    }
    #pragma unroll
    for (int f=0; f<4; ++f){
      int hcol = colBase + f*16 + lr;
      float bn = bhn1[hcol];
      #pragma unroll
      for (int r=0;r<4;++r){
        int row = rowBase + w*16 + lq*4 + r;
        size_t gb = (size_t)row*H3 + hcol;
        float g_r = __builtin_nontemporal_load(&gi1[gb]);
        float g_z = __builtin_nontemporal_load(&gi1[gb + HH]);
        float g_n = __builtin_nontemporal_load(&gi1[gb + 2*HH]);
        float hv  = hp1[(size_t)row*HH + hcol] * mask_t[row];
        float rg = sigm(g_r + acc[f][r]);
        float zg = sigm(g_z + acc[4+f][r]);
        float ng = tanhf(g_n + rg*(acc[8+f][r] + bn));
        ho1[(size_t)row*HH + hcol] = (1.f - zg)*ng + zg*hv;
      }
    }
  }
}

// ---------------- logits + first-max argmax (chunked: t = t0 + local) ----------------
__global__ __launch_bounds__(256) void k_logits(const float* __restrict__ ae2,
    const float* __restrict__ e, float* __restrict__ out_logits, int* __restrict__ argk, int t0)
{
  __shared__ float es[KK*SS];
  int tid = threadIdx.x;
  for (int i=0;i<4;++i) es[tid + i*256] = e[tid + i*256];
  __syncthreads();
  int g = blockIdx.x*256 + tid;
  int t = t0 + (g >> 10), j = g & 1023;
  const float* arow = &ae2[(size_t)g * SS];
  float a[SS];
  #pragma unroll
  for (int i=0;i<16;++i){ float4 v = ((const float4*)arow)[i]; a[4*i]=v.x; a[4*i+1]=v.y; a[4*i+2]=v.z; a[4*i+3]=v.w; }
  float lg[KK];
  float best = -INFINITY; int bk = 0;
  for (int k=0;k<KK;++k){
    float s2 = 0.f;
    #pragma unroll 8
    for (int s=0;s<SS;++s) s2 += a[s]*es[k*SS+s];
    lg[k] = s2;
    if (s2 > best){ best = s2; bk = k; }
  }
  int n = j >> 7, b = j & 127;
  size_t ob = ((size_t)((t*BB + b)*NN + n)) * KK;
  #pragma unroll
  for (int k4=0;k4<4;++k4)
    *(float4*)&out_logits[ob + k4*4] = make_float4(lg[k4*4],lg[k4*4+1],lg[k4*4+2],lg[k4*4+3]);
  argk[(t*BB + b)*NN + n] = bk;   // (b,n)-major: matches reference's prob/q index quirk
}

// ---------------- q selection (chunked) ----------------
__global__ __launch_bounds__(64) void k_qsel(const float* __restrict__ y2,
    const float* __restrict__ w1, const float* __restrict__ b1,
    const int* __restrict__ argk, float* __restrict__ outq)
{
  __shared__ float yr[HH];
  __shared__ float part[64];
  int bj = blockIdx.x;
  int tid = threadIdx.x;
  const float4* row4 = (const float4*)&y2[(size_t)bj*HH];
  ((float4*)yr)[tid]    = row4[tid];
  ((float4*)yr)[tid+64] = row4[tid+64];
  __syncthreads();
  int k = argk[bj];
  int a = tid & 15, q4 = tid >> 4;
  const float* wp = &w1[(size_t)k*HH*AA + a];
  float s = 0.f;
  int h0 = q4*128;
  #pragma unroll 8
  for (int h=h0; h<h0+128; ++h) s += yr[h]*wp[(size_t)h*AA];
  part[tid] = s;
  __syncthreads();
  if (q4 == 0){
    float v = part[a] + part[a+16] + part[a+32] + part[a+48] + b1[k*AA + a];
    outq[(size_t)bj*AA + a] = v;
  }
}

// ---------------- orchestration ----------------
extern "C" void kernel_launch(void* const* d_in, const int* in_sizes, int n_in,
                              void* d_out, int out_size, void* d_ws, size_t ws_size,
                              hipStream_t stream)
{
  (void)in_sizes; (void)n_in; (void)out_size;
  const float* h1     = (const float*)d_in[0];
  const float* h2     = (const float*)d_in[1];
  const float* obs    = (const float*)d_in[2];
  const unsigned char* done_raw = (const unsigned char*)d_in[3];
  const float* W_embed=(const float*)d_in[4];  const float* b_embed=(const float*)d_in[5];
  const float* Wi1    =(const float*)d_in[6];  const float* bi1    =(const float*)d_in[7];
  const float* Wh1    =(const float*)d_in[8];  const float* bhn1   =(const float*)d_in[9];
  const float* W_sub  =(const float*)d_in[10]; const float* b_sub  =(const float*)d_in[11];
  const float* W_e1   =(const float*)d_in[12]; const float* b_e1   =(const float*)d_in[13];
  const float* W_e2   =(const float*)d_in[14]; const float* b_e2   =(const float*)d_in[15];
  const float* W_pol  =(const float*)d_in[16]; const float* b_pol  =(const float*)d_in[17];
  const float* Wi2    =(const float*)d_in[18]; const float* bi2    =(const float*)d_in[19];
  const float* Wh2    =(const float*)d_in[20]; const float* bhn2   =(const float*)d_in[21];
  const float* W_w1   =(const float*)d_in[22]; const float* b_w1   =(const float*)d_in[23];
  const float* W_b1   =(const float*)d_in[24]; const float* b_b1   =(const float*)d_in[25];

  float* out    = (float*)d_out;
  float* outHT1 = out;
  float* outHT2 = out + (size_t)NB*HH;
  float* outQ   = out + 2ull*NB*HH;
  float* outLG  = outQ + (size_t)TT*NB*AA;
  float* outSE  = outLG + (size_t)TT*BB*NN*KK;

  // ---- adaptive chunk size (float units) ----
  const size_t fixed_f = 2ull*NB*HH + (size_t)TT*NB + 1024
                       + (size_t)KK*HH*AA + 256 + (size_t)TT*NB + 64
                       + 2ull*DD*HH/2 * 2            // wembT, wpolT hi+lo pairs
                       + 4ull*H3*HH                  // wi1T,wi2T,wh1T,wh2T hi+lo pairs
                       + (size_t)HH*SS;              // wsubT hi+lo
  const size_t per_t_f = (size_t)NB*(2*HH + 2*H3 + SS)         // buf1,buf2,gbuf1,gbuf2,ae2buf
                       + (size_t)NB*(HH/2 + DD + HH + HH);     // buf2bf, obs pair, ae pair, y1 pair
  int CH = 64;
  while (CH > 1 && (fixed_f + per_t_f*(size_t)CH)*4 > ws_size) CH >>= 1;

  float* buf1   = (float*)d_ws;                        // y1 chunk: CH*NB*HH
  float* buf2   = buf1   + (size_t)CH*NB*HH;           // y2 chunk
  float* gbuf1  = buf2   + (size_t)CH*NB*HH;           // gi1 chunk
  float* gbuf2  = gbuf1  + (size_t)CH*NB*H3;           // gi2 chunk
  float* ae2buf = gbuf2  + (size_t)CH*NB*H3;           // CH*NB*SS
  float* h_last1= ae2buf + (size_t)CH*NB*SS;
  float* h_last2= h_last1+ (size_t)NB*HH;
  float* maskp  = h_last2+ (size_t)NB*HH;
  float* ws_e   = maskp  + (size_t)TT*NB;
  float* ws_w1  = ws_e   + 1024;
  float* ws_b1  = ws_w1  + (size_t)KK*HH*AA;
  int*   ws_argk= (int*)(ws_b1 + 256);
  int*   ws_flag= (int*)(ws_argk + (size_t)TT*NB);
  unsigned short* buf2bf = (unsigned short*)(ws_flag + 64);   // CH*NB*HH bf16 (sp)
  unsigned short* obs_h  = buf2bf + (size_t)CH*NB*HH;         // CH*NB*DD
  unsigned short* obs_l  = obs_h  + (size_t)CH*NB*DD;
  unsigned short* ae_h   = obs_l  + (size_t)CH*NB*DD;         // CH*NB*HH
  unsigned short* ae_l   = ae_h   + (size_t)CH*NB*HH;
  unsigned short* y1_h   = ae_l   + (size_t)CH*NB*HH;
  unsigned short* y1_l   = y1_h   + (size_t)CH*NB*HH;
  unsigned short* wembt_h= y1_l   + (size_t)CH*NB*HH;         // 512*128
  unsigned short* wembt_l= wembt_h+ (size_t)HH*DD;
  unsigned short* wpolt_h= wembt_l+ (size_t)HH*DD;
  unsigned short* wpolt_l= wpolt_h+ (size_t)HH*DD;
  unsigned short* wi1t_h = wpolt_l+ (size_t)HH*DD;            // 1536*512 each
  unsigned short* wi1t_l = wi1t_h + (size_t)H3*HH;
  unsigned short* wi2t_h = wi1t_l + (size_t)H3*HH;
  unsigned short* wi2t_l = wi2t_h + (size_t)H3*HH;
  unsigned short* wh1t_h = wi2t_l + (size_t)H3*HH;
  unsigned short* wh1t_l = wh1t_h + (size_t)H3*HH;
  unsigned short* wh2t_h = wh1t_l + (size_t)H3*HH;
  unsigned short* wh2t_l = wh2t_h + (size_t)H3*HH;
  unsigned short* wsubt_h= wh2t_l + (size_t)H3*HH;            // 64*512
  unsigned short* wsubt_l= wsubt_h+ (size_t)SS*HH;

  // phase 0
  k_detect<<<1,256,0,stream>>>(done_raw, ws_flag);
  k_mask<<<TT*NB/256,256,0,stream>>>(done_raw, ws_flag, maskp);
  k_e<<<1,256,0,stream>>>(W_e1,b_e1,W_e2,b_e2,ws_e);
  k_w1b1<<<128,256,0,stream>>>(ws_e,W_w1,b_w1,W_b1,b_b1,ws_w1,ws_b1);
  k_se<<<2048,256,0,stream>>>(ws_e,outSE);
  k_tsplit<<<dim3(16,4),256,0,stream>>>(W_embed, wembt_h, wembt_l, DD, HH);
  k_tsplit<<<dim3(16,4),256,0,stream>>>(W_pol,   wpolt_h, wpolt_l, DD, HH);
  k_tsplit<<<dim3(48,16),256,0,stream>>>(Wi1, wi1t_h, wi1t_l, HH, H3);
  k_tsplit<<<dim3(48,16),256,0,stream>>>(Wi2, wi2t_h, wi2t_l, HH, H3);
  k_tsplit<<<dim3(48,16),256,0,stream>>>(Wh1, wh1t_h, wh1t_l, HH, H3);
  k_tsplit<<<dim3(48,16),256,0,stream>>>(Wh2, wh2t_h, wh2t_l, HH, H3);
  k_tsplit<<<dim3(2,16),256,0,stream>>>(W_sub, wsubt_h, wsubt_l, HH, SS);
  k_copy<<<512,256,0,stream>>>(h1, h_last1, NB*HH/4);
  k_copy<<<512,256,0,stream>>>(h2, h_last2, NB*HH/4);

  dim3 thr(256);
  const int NCH = TT / CH;
  for (int c = 0; c < NCH; ++c){
    int t0 = c * CH;
    int M = CH*NB;
    const float* obs_c = obs + (size_t)t0*NB*DD;
    // obs split-cast
    k_split_cast<<<(M*DD/8+255)/256,256,0,stream>>>(obs_c, obs_h, obs_l, M*DD/8);
    // branch-1 front: embed1 (split, writes ae pair) -> gi1 (split, fp32 out)
    mfma_gemm<DD,1,128,1,2><<<dim3(HH/128, M/128),thr,0,stream>>>(
        obs_h, obs_l, wembt_h, wembt_l, b_embed, nullptr, ae_h, ae_l, HH);
    mfma_gemm<HH,1,128,0,0><<<dim3(H3/128, M/128),thr,0,stream>>>(
        ae_h, ae_l, wi1t_h, wi1t_l, bi1, gbuf1, nullptr, nullptr, H3);
    // branch-2 front: embed2 (plain, bf16 out) -> gi2 (plain, fp32 out)
    mfma_gemm<DD,0,128,1,1><<<dim3(HH/128, M/128),thr,0,stream>>>(
        obs_h, obs_h, wpolt_h, wpolt_h, b_pol, nullptr, buf2bf, nullptr, HH);
    mfma_gemm<HH,0,128,0,0><<<dim3(H3/128, M/128),thr,0,stream>>>(
        buf2bf, buf2bf, wi2t_h, wi2t_h, bi2, gbuf2, nullptr, nullptr, H3);
    // dual-GRU scan (validated)
    for (int lt = 0; lt < CH; ++lt){
      const float* hp1 = (lt == 0) ? h_last1 : (buf1 + (size_t)(lt-1)*NB*HH);
      const float* hp2 = (lt == 0) ? h_last2 : (buf2 + (size_t)(lt-1)*NB*HH);
      gru_step_mix2<<<256, 256, 0, stream>>>(hp1, hp2,
                                             gbuf1 + (size_t)lt*NB*H3, gbuf2 + (size_t)lt*NB*H3,
                                             wh1t_h, wh1t_l, wh2t_h, bhn1, bhn2,
                                             maskp + (size_t)(t0+lt)*NB,
                                             buf1 + (size_t)lt*NB*HH, buf2 + (size_t)lt*NB*HH);
    }
    k_copy<<<512,256,0,stream>>>(buf1 + (size_t)(CH-1)*NB*HH, h_last1, NB*HH/4);
    k_copy<<<512,256,0,stream>>>(buf2 + (size_t)(CH-1)*NB*HH, h_last2, NB*HH/4);
    // tails: ae2 via split MFMA (N=64), then logits + qsel
    k_split_cast<<<(M*HH/8+255)/256,256,0,stream>>>(buf1, y1_h, y1_l, M*HH/8);
    mfma_gemm<HH,1,64,0,0><<<dim3(1, M/128),thr,0,stream>>>(
        y1_h, y1_l, wsubt_h, wsubt_l, b_sub, ae2buf, nullptr, nullptr, SS);
    k_logits<<<M/256,256,0,stream>>>(ae2buf, ws_e, outLG, ws_argk, t0);
    k_qsel<<<M,64,0,stream>>>(buf2, ws_w1, ws_b1, ws_argk + (size_t)t0*NB, outQ + (size_t)t0*NB*AA);
  }
  k_copy<<<512,256,0,stream>>>(h_last1, outHT1, NB*HH/4);
  k_copy<<<512,256,0,stream>>>(h_last2, outHT2, NB*HH/4);
}

// Round 11
// 3142.869 us; speedup vs baseline: 7.6421x; 1.4933x over previous
//
#include <hip/hip_runtime.h>
#include <hip/hip_bf16.h>
#include <math.h>

#define TT 64
#define NN 8
#define BB 128
#define DD 128
#define HH 512
#define SS 64
#define KK 16
#define AA 16
#define NB 1024
#define H3 (3*HH)       /* 1536 */

typedef float f4v  __attribute__((ext_vector_type(4)));
typedef float f16v __attribute__((ext_vector_type(16)));
typedef short bf16x8 __attribute__((ext_vector_type(8)));

__device__ __forceinline__ float sigm(float x){ return 1.0f/(1.0f+expf(-x)); }
__device__ __forceinline__ unsigned short f2bf(float f){
  unsigned u = __float_as_uint(f);
  u += 0x7FFF + ((u >> 16) & 1);          // round-to-nearest-even
  return (unsigned short)(u >> 16);
}
__device__ __forceinline__ float bf2f(unsigned short h){
  return __uint_as_float(((unsigned)h) << 16);
}

// ---------------- done-layout detection + mask expansion ----------------
__global__ __launch_bounds__(256) void k_detect(const unsigned char* __restrict__ raw,
                                                int* __restrict__ flag)
{
  __shared__ int cA, cB;
  if (threadIdx.x == 0){ cA = 0; cB = 0; }
  __syncthreads();
  int a = 0, b = 0;
  for (int i = threadIdx.x; i < TT*NB; i += 256){
    unsigned char v = raw[i];
    if (v > 1) a++;
    if ((i & 3) != 0 && v != 0) b++;
  }
  atomicAdd(&cA, a); atomicAdd(&cB, b);
  __syncthreads();
  if (threadIdx.x == 0) *flag = (cB == 0) ? 0 : (cA == 0 ? 1 : 2);
}

__global__ __launch_bounds__(256) void k_mask(const unsigned char* __restrict__ raw,
                                              const int* __restrict__ flag,
                                              float* __restrict__ mask)
{
  int i = blockIdx.x*256 + threadIdx.x;
  if (i >= TT*NB) return;
  int f = *flag;
  int v;
  if (f == 1)      v = (int)raw[i];
  else if (f == 0) v = ((const int*)raw)[i];
  else             v = (((const float*)raw)[i] != 0.0f);
  mask[i] = v ? 0.f : 1.f;   // 0 => reset carry
}

// ---------------- small setup kernels ----------------

__global__ __launch_bounds__(256) void k_e(const float* __restrict__ W_e1, const float* __restrict__ b_e1,
                                           const float* __restrict__ W_e2, const float* __restrict__ b_e2,
                                           float* __restrict__ e_out)
{
  __shared__ float r1[KK*SS];
  int tid = threadIdx.x;
  for (int i=0;i<4;++i){ int l = tid + i*256; float v = W_e1[l] + b_e1[l & 63]; r1[l] = v > 0.f ? v : 0.f; }
  __syncthreads();
  for (int i=0;i<4;++i){
    int l = tid + i*256; int k = l >> 6, s = l & 63;
    float acc = b_e2[s];
    #pragma unroll 8
    for (int sp=0; sp<64; ++sp) acc += r1[k*64+sp] * W_e2[sp*64 + s];
    e_out[l] = tanhf(acc);
  }
}

__global__ __launch_bounds__(256) void k_w1b1(const float* __restrict__ e, const float* __restrict__ W_w1,
                                              const float* __restrict__ b_w1, const float* __restrict__ W_b1,
                                              const float* __restrict__ b_b1, float* __restrict__ w1,
                                              float* __restrict__ b1)
{
  __shared__ float es[KK*SS];
  int tid = threadIdx.x;
  for (int i=0;i<4;++i) es[tid + i*256] = e[tid + i*256];
  __syncthreads();
  for (int i=0;i<4;++i){
    int l = blockIdx.x*1024 + tid + i*256;
    int k = l >> 13, m = l & 8191;
    float acc = b_w1[m];
    #pragma unroll 8
    for (int s=0;s<64;++s) acc += es[k*64+s] * W_w1[(size_t)s*8192 + m];
    w1[l] = acc;
  }
  if (blockIdx.x == 0){
    int k = tid >> 4, a = tid & 15;
    float acc = b_b1[a];
    #pragma unroll 8
    for (int s=0;s<64;++s) acc += es[k*64+s] * W_b1[s*16 + a];
    b1[tid] = acc;
  }
}

__global__ __launch_bounds__(256) void k_se(const float* __restrict__ e, float* __restrict__ outse)
{
  __shared__ float4 es[256];
  es[threadIdx.x] = ((const float4*)e)[threadIdx.x];
  __syncthreads();
  const int total4 = TT*BB*KK*SS/4;
  for (int i = blockIdx.x*256 + threadIdx.x; i < total4; i += gridDim.x*256)
    ((float4*)outse)[i] = es[i & 255];
}

__global__ void k_copy(const float* __restrict__ src, float* __restrict__ dst, int n4)
{
  int i = blockIdx.x*blockDim.x + threadIdx.x;
  if (i < n4) ((float4*)dst)[i] = ((const float4*)src)[i];
}

// generic transpose + split: W [Kd][Nc] f32 -> WTh/WTl [Nc][Kd] bf16
__global__ __launch_bounds__(256) void k_tsplit(const float* __restrict__ W,
                                                unsigned short* __restrict__ WTh,
                                                unsigned short* __restrict__ WTl,
                                                int Kd, int Nc)
{
  __shared__ float t[32][33];
  int n0 = blockIdx.x * 32;
  int k0 = blockIdx.y * 32;
  int c = threadIdx.x & 31, r8 = threadIdx.x >> 5;
  for (int i=0;i<4;++i){
    int r = r8 + i*8;
    t[r][c] = W[(size_t)(k0+r)*Nc + n0 + c];
  }
  __syncthreads();
  for (int i=0;i<4;++i){
    int nr = r8 + i*8;
    float v = t[c][nr];
    unsigned short hi = f2bf(v);
    WTh[(size_t)(n0+nr)*Kd + k0 + c] = hi;
    WTl[(size_t)(n0+nr)*Kd + k0 + c] = f2bf(v - bf2f(hi));
  }
}

// f32 -> (hi, lo) bf16 flat split-cast, 8 elems/thread
__global__ void k_split_cast(const float* __restrict__ src,
                             unsigned short* __restrict__ dh,
                             unsigned short* __restrict__ dl, int n8)
{
  int i = blockIdx.x*blockDim.x + threadIdx.x;
  if (i >= n8) return;
  const float4* s = (const float4*)(src + (size_t)i*8);
  float4 a = s[0], b = s[1];
  float x[8] = {a.x,a.y,a.z,a.w,b.x,b.y,b.z,b.w};
  union { unsigned short u[8]; uint4 v; } ph, pl;
  #pragma unroll
  for (int j=0;j<8;++j){
    unsigned short hi = f2bf(x[j]);
    ph.u[j] = hi;
    pl.u[j] = f2bf(x[j] - bf2f(hi));
  }
  *(uint4*)&dh[(size_t)i*8] = ph.v;
  *(uint4*)&dl[(size_t)i*8] = pl.v;
}

// ---------------- unified MFMA GEMM (validated round 10) ----------------
template<int KD, int SPLIT, int NTILE, int RELU, int OUTMODE>
__global__ __launch_bounds__(256) void mfma_gemm(
    const unsigned short* Ah, const unsigned short* Al,
    const unsigned short* Bh, const unsigned short* Bl,
    const float* __restrict__ bias,
    float* C, unsigned short* Chi, unsigned short* Clo, int Nstride)
{
  constexpr int NFC = NTILE/16;
  __shared__ __align__(16) unsigned short AsH[128*40];
  __shared__ __align__(16) unsigned short BsH[NTILE*40];
  __shared__ __align__(16) unsigned short AsL[SPLIT ? 128*40 : 8];
  __shared__ __align__(16) unsigned short BsL[SPLIT ? NTILE*40 : 8];
  int tid = threadIdx.x;
  int w = tid >> 6, l = tid & 63;
  int lr = l & 15, lk = (l >> 4) * 8, lq = l >> 4;
  int rowBase = blockIdx.y * 128, colBase = blockIdx.x * NTILE;
  f4v acc[2][NFC];
  f4v z = {0.f,0.f,0.f,0.f};
  #pragma unroll
  for (int i=0;i<2;++i)
    #pragma unroll
    for (int j=0;j<NFC;++j) acc[i][j] = z;

  for (int k0 = 0; k0 < KD; k0 += 32){
    {
      int r = tid >> 1, half = tid & 1;
      size_t src = (size_t)(rowBase + r)*KD + k0 + half*16;
      bf16x8* dA = (bf16x8*)&AsH[r*40 + half*16];
      dA[0] = *(const bf16x8*)&Ah[src];
      dA[1] = *(const bf16x8*)&Ah[src + 8];
      if (SPLIT){
        bf16x8* dL = (bf16x8*)&AsL[r*40 + half*16];
        dL[0] = *(const bf16x8*)&Al[src];
        dL[1] = *(const bf16x8*)&Al[src + 8];
      }
    }
    if (NTILE == 128){
      int r = tid >> 1, half = tid & 1;
      size_t src = (size_t)(colBase + r)*KD + k0 + half*16;
      bf16x8* dB = (bf16x8*)&BsH[r*40 + half*16];
      dB[0] = *(const bf16x8*)&Bh[src];
      dB[1] = *(const bf16x8*)&Bh[src + 8];
      if (SPLIT){
        bf16x8* dL = (bf16x8*)&BsL[r*40 + half*16];
        dL[0] = *(const bf16x8*)&Bl[src];
        dL[1] = *(const bf16x8*)&Bl[src + 8];
      }
    } else {   // NTILE == 64
      int r = tid >> 2, q = tid & 3;
      size_t src = (size_t)(colBase + r)*KD + k0 + q*8;
      *(bf16x8*)&BsH[r*40 + q*8] = *(const bf16x8*)&Bh[src];
      if (SPLIT)
        *(bf16x8*)&BsL[r*40 + q*8] = *(const bf16x8*)&Bl[src];
    }
    __syncthreads();
    bf16x8 aH0 = *(const bf16x8*)&AsH[(w*32 + lr)*40 + lk];
    bf16x8 aH1 = *(const bf16x8*)&AsH[(w*32 + 16 + lr)*40 + lk];
    bf16x8 aL0, aL1;
    if (SPLIT){
      aL0 = *(const bf16x8*)&AsL[(w*32 + lr)*40 + lk];
      aL1 = *(const bf16x8*)&AsL[(w*32 + 16 + lr)*40 + lk];
    }
    #pragma unroll
    for (int fc=0; fc<NFC; ++fc){
      bf16x8 bH = *(const bf16x8*)&BsH[(fc*16 + lr)*40 + lk];
      acc[0][fc] = __builtin_amdgcn_mfma_f32_16x16x32_bf16(aH0, bH, acc[0][fc], 0,0,0);
      acc[1][fc] = __builtin_amdgcn_mfma_f32_16x16x32_bf16(aH1, bH, acc[1][fc], 0,0,0);
      if (SPLIT){
        bf16x8 bL = *(const bf16x8*)&BsL[(fc*16 + lr)*40 + lk];
        acc[0][fc] = __builtin_amdgcn_mfma_f32_16x16x32_bf16(aH0, bL, acc[0][fc], 0,0,0);
        acc[1][fc] = __builtin_amdgcn_mfma_f32_16x16x32_bf16(aH1, bL, acc[1][fc], 0,0,0);
        acc[0][fc] = __builtin_amdgcn_mfma_f32_16x16x32_bf16(aL0, bH, acc[0][fc], 0,0,0);
        acc[1][fc] = __builtin_amdgcn_mfma_f32_16x16x32_bf16(aL1, bH, acc[1][fc], 0,0,0);
      }
    }
    __syncthreads();
  }
  #pragma unroll
  for (int fr=0; fr<2; ++fr){
    #pragma unroll
    for (int fc=0; fc<NFC; ++fc){
      int col = colBase + fc*16 + lr;
      float bv = bias[col];
      #pragma unroll
      for (int r=0;r<4;++r){
        int row = rowBase + w*32 + fr*16 + lq*4 + r;
        float v = acc[fr][fc][r] + bv;
        if (RELU) v = v > 0.f ? v : 0.f;
        size_t o = (size_t)row*Nstride + col;
        if (OUTMODE == 0) C[o] = v;
        else if (OUTMODE == 1) Chi[o] = f2bf(v);
        else {
          unsigned short hi = f2bf(v);
          Chi[o] = hi;
          Clo[o] = f2bf(v - bf2f(hi));
        }
      }
    }
  }
}

// ---------------- per-step GRU, 32x32x16 MFMA + register-prefetch double-buffer ----------------
// 256 blocks: bid<128 GRU2 (plain bf16), else GRU1 (split hi/lo, ~fp32).
// Block tile: 64 rows x 64 h-cols (192 gate-cols). Wave w: row-frag rf=w&1 (32 rows),
// h-col half hc=w>>1 (32 cols), 3 gate frags. GRU1 epilogue also writes y1 hi/lo pair.
__global__ __launch_bounds__(256) void gru_step_mix3(
    const float* __restrict__ hp1, const float* __restrict__ hp2,
    const float* __restrict__ gi1, const float* __restrict__ gi2,
    const unsigned short* __restrict__ Wh1TH, const unsigned short* __restrict__ Wh1TL,
    const unsigned short* __restrict__ Wh2T,
    const float* __restrict__ bhn1, const float* __restrict__ bhn2,
    const float* __restrict__ mask_t,
    float* __restrict__ ho1, float* __restrict__ ho2,
    unsigned short* __restrict__ y1h, unsigned short* __restrict__ y1l)
{
  __shared__ __align__(16) char smem[40960];
  int bid = blockIdx.x;
  int tid = threadIdx.x;
  int w = tid >> 6, l = tid & 63;
  int rf = w & 1, hc = w >> 1;
  int lc = l & 31, lh = l >> 5;          // frag col lane / k-oct (and +4-row select in C)
  int sr = tid >> 2, sg = tid & 3;       // A staging: row, 8-float group
  f16v z16 = {0,0,0,0,0,0,0,0,0,0,0,0,0,0,0,0};

  if (bid < 128){
    // ===== GRU2: plain bf16, 32x32x16 =====
    unsigned short* As = (unsigned short*)smem;            // [64][40]
    unsigned short* Bs = (unsigned short*)smem + 64*40;    // [192][40]
    int ct = bid & 7, rt = bid >> 3;
    int rowBase = rt << 6, colBase = ct << 6;
    float m_st = mask_t[rowBase + sr];                     // staging-row mask (hoisted)
    f16v acc[3] = {z16, z16, z16};

    float4 pA0, pA1;
    bf16x8 pB[3];
    {
      const float4* s = (const float4*)&hp2[(size_t)(rowBase + sr)*HH + sg*8];
      pA0 = s[0]; pA1 = s[1];
      #pragma unroll
      for (int i=0;i<3;++i){
        int unit = i*256 + tid, brow = unit >> 2, q = unit & 3;
        int g = brow >> 6, c = brow & 63;
        pB[i] = *(const bf16x8*)&Wh2T[(size_t)(g*HH + colBase + c)*HH + q*8];
      }
    }
    for (int k0 = 0; k0 < HH; k0 += 32){
      __syncthreads();
      {
        float x[8] = {pA0.x*m_st,pA0.y*m_st,pA0.z*m_st,pA0.w*m_st,
                      pA1.x*m_st,pA1.y*m_st,pA1.z*m_st,pA1.w*m_st};
        union { unsigned short u[8]; uint4 v; } p;
        #pragma unroll
        for (int j=0;j<8;++j) p.u[j] = f2bf(x[j]);
        *(uint4*)&As[sr*40 + sg*8] = p.v;
        #pragma unroll
        for (int i=0;i<3;++i){
          int unit = i*256 + tid, brow = unit >> 2, q = unit & 3;
          *(bf16x8*)&Bs[brow*40 + q*8] = pB[i];
        }
      }
      __syncthreads();
      if (k0 + 32 < HH){
        const float4* s = (const float4*)&hp2[(size_t)(rowBase + sr)*HH + k0 + 32 + sg*8];
        pA0 = s[0]; pA1 = s[1];
        #pragma unroll
        for (int i=0;i<3;++i){
          int unit = i*256 + tid, brow = unit >> 2, q = unit & 3;
          int g = brow >> 6, c = brow & 63;
          pB[i] = *(const bf16x8*)&Wh2T[(size_t)(g*HH + colBase + c)*HH + k0 + 32 + q*8];
        }
      }
      #pragma unroll
      for (int kc=0;kc<32;kc+=16){
        bf16x8 a = *(const bf16x8*)&As[(rf*32 + lc)*40 + kc + lh*8];
        #pragma unroll
        for (int g=0; g<3; ++g){
          bf16x8 b = *(const bf16x8*)&Bs[(g*64 + hc*32 + lc)*40 + kc + lh*8];
          acc[g] = __builtin_amdgcn_mfma_f32_32x32x16_bf16(a, b, acc[g], 0,0,0);
        }
      }
    }
    int col = colBase + hc*32 + lc;
    float bn = bhn2[col];
    #pragma unroll
    for (int r=0;r<16;++r){
      int row = rowBase + rf*32 + (r&3) + 8*(r>>2) + 4*lh;
      size_t gb = (size_t)row*H3 + col;
      float g_r = __builtin_nontemporal_load(&gi2[gb]);
      float g_z = __builtin_nontemporal_load(&gi2[gb + HH]);
      float g_n = __builtin_nontemporal_load(&gi2[gb + 2*HH]);
      float hv  = hp2[(size_t)row*HH + col] * mask_t[row];   // exact (branch-2 margin)
      float rg = sigm(g_r + acc[0][r]);
      float zg = sigm(g_z + acc[1][r]);
      float ng = tanhf(g_n + rg*(acc[2][r] + bn));
      ho2[(size_t)row*HH + col] = (1.f - zg)*ng + zg*hv;
    }
  } else {
    // ===== GRU1: split hi/lo, 32x32x16, ~fp32 precision =====
    unsigned short* AsH = (unsigned short*)smem;             // [64][40]
    unsigned short* AsL = AsH + 64*40;
    unsigned short* BsH = AsL + 64*40;                       // [192][40]
    unsigned short* BsL = BsH + 192*40;
    int bidp = bid - 128;
    int ct = bidp & 7, rt = bidp >> 3;
    int rowBase = rt << 6, colBase = ct << 6;
    int capk = colBase + hc*32;                              // k-chunk holding own h-cols
    float m_st = mask_t[rowBase + sr];
    f16v acc[3] = {z16, z16, z16};
    float hval[16];

    float4 pA0, pA1;
    bf16x8 pBH[3], pBL[3];
    {
      const float4* s = (const float4*)&hp1[(size_t)(rowBase + sr)*HH + sg*8];
      pA0 = s[0]; pA1 = s[1];
      #pragma unroll
      for (int i=0;i<3;++i){
        int unit = i*256 + tid, brow = unit >> 2, q = unit & 3;
        int g = brow >> 6, c = brow & 63;
        size_t src = (size_t)(g*HH + colBase + c)*HH + q*8;
        pBH[i] = *(const bf16x8*)&Wh1TH[src];
        pBL[i] = *(const bf16x8*)&Wh1TL[src];
      }
    }
    for (int k0 = 0; k0 < HH; k0 += 32){
      __syncthreads();
      {
        float x[8] = {pA0.x*m_st,pA0.y*m_st,pA0.z*m_st,pA0.w*m_st,
                      pA1.x*m_st,pA1.y*m_st,pA1.z*m_st,pA1.w*m_st};
        union { unsigned short u[8]; uint4 v; } ph, pl;
        #pragma unroll
        for (int j=0;j<8;++j){
          unsigned short hi = f2bf(x[j]);
          ph.u[j] = hi;
          pl.u[j] = f2bf(x[j] - bf2f(hi));
        }
        *(uint4*)&AsH[sr*40 + sg*8] = ph.v;
        *(uint4*)&AsL[sr*40 + sg*8] = pl.v;
        #pragma unroll
        for (int i=0;i<3;++i){
          int unit = i*256 + tid, brow = unit >> 2, q = unit & 3;
          *(bf16x8*)&BsH[brow*40 + q*8] = pBH[i];
          *(bf16x8*)&BsL[brow*40 + q*8] = pBL[i];
        }
      }
      __syncthreads();
      if (k0 + 32 < HH){
        const float4* s = (const float4*)&hp1[(size_t)(rowBase + sr)*HH + k0 + 32 + sg*8];
        pA0 = s[0]; pA1 = s[1];
        #pragma unroll
        for (int i=0;i<3;++i){
          int unit = i*256 + tid, brow = unit >> 2, q = unit & 3;
          int g = brow >> 6, c = brow & 63;
          size_t src = (size_t)(g*HH + colBase + c)*HH + k0 + 32 + q*8;
          pBH[i] = *(const bf16x8*)&Wh1TH[src];
          pBL[i] = *(const bf16x8*)&Wh1TL[src];
        }
      }
      if (k0 == capk){                 // masked h_prev at own columns (hi+lo, err ~2^-17)
        #pragma unroll
        for (int r=0;r<16;++r){
          int rl = rf*32 + (r&3) + 8*(r>>2) + 4*lh;
          hval[r] = bf2f(AsH[rl*40 + lc]) + bf2f(AsL[rl*40 + lc]);
        }
      }
      #pragma unroll
      for (int kc=0;kc<32;kc+=16){
        bf16x8 aH = *(const bf16x8*)&AsH[(rf*32 + lc)*40 + kc + lh*8];
        bf16x8 aL = *(const bf16x8*)&AsL[(rf*32 + lc)*40 + kc + lh*8];
        #pragma unroll
        for (int g=0; g<3; ++g){
          int brow = (g*64 + hc*32 + lc)*40 + kc + lh*8;
          bf16x8 bH = *(const bf16x8*)&BsH[brow];
          bf16x8 bL = *(const bf16x8*)&BsL[brow];
          acc[g] = __builtin_amdgcn_mfma_f32_32x32x16_bf16(aH, bH, acc[g], 0,0,0);
          acc[g] = __builtin_amdgcn_mfma_f32_32x32x16_bf16(aH, bL, acc[g], 0,0,0);
          acc[g] = __builtin_amdgcn_mfma_f32_32x32x16_bf16(aL, bH, acc[g], 0,0,0);
        }
      }
    }
    int col = colBase + hc*32 + lc;
    float bn = bhn1[col];
    #pragma unroll
    for (int r=0;r<16;++r){
      int row = rowBase + rf*32 + (r&3) + 8*(r>>2) + 4*lh;
      size_t gb = (size_t)row*H3 + col;
      float g_r = __builtin_nontemporal_load(&gi1[gb]);
      float g_z = __builtin_nontemporal_load(&gi1[gb + HH]);
      float g_n = __builtin_nontemporal_load(&gi1[gb + 2*HH]);
      float rg = sigm(g_r + acc[0][r]);
      float zg = sigm(g_z + acc[1][r]);
      float ng = tanhf(g_n + rg*(acc[2][r] + bn));
      float o  = (1.f - zg)*ng + zg*hval[r];
      size_t oo = (size_t)row*HH + col;
      ho1[oo] = o;
      unsigned short hi = f2bf(o);                 // fused y1 split store (feeds ae2 MFMA)
      __builtin_nontemporal_store(hi, &y1h[oo]);
      __builtin_nontemporal_store(f2bf(o - bf2f(hi)), &y1l[oo]);
    }
  }
}

// ---------------- logits + first-max argmax (chunked: t = t0 + local) ----------------
__global__ __launch_bounds__(256) void k_logits(const float* __restrict__ ae2,
    const float* __restrict__ e, float* __restrict__ out_logits, int* __restrict__ argk, int t0)
{
  __shared__ float es[KK*SS];
  int tid = threadIdx.x;
  for (int i=0;i<4;++i) es[tid + i*256] = e[tid + i*256];
  __syncthreads();
  int g = blockIdx.x*256 + tid;
  int t = t0 + (g >> 10), j = g & 1023;
  const float* arow = &ae2[(size_t)g * SS];
  float a[SS];
  #pragma unroll
  for (int i=0;i<16;++i){ float4 v = ((const float4*)arow)[i]; a[4*i]=v.x; a[4*i+1]=v.y; a[4*i+2]=v.z; a[4*i+3]=v.w; }
  float lg[KK];
  float best = -INFINITY; int bk = 0;
  for (int k=0;k<KK;++k){
    float s2 = 0.f;
    #pragma unroll 8
    for (int s=0;s<SS;++s) s2 += a[s]*es[k*SS+s];
    lg[k] = s2;
    if (s2 > best){ best = s2; bk = k; }
  }
  int n = j >> 7, b = j & 127;
  size_t ob = ((size_t)((t*BB + b)*NN + n)) * KK;
  #pragma unroll
  for (int k4=0;k4<4;++k4)
    *(float4*)&out_logits[ob + k4*4] = make_float4(lg[k4*4],lg[k4*4+1],lg[k4*4+2],lg[k4*4+3]);
  argk[(t*BB + b)*NN + n] = bk;   // (b,n)-major: matches reference's prob/q index quirk
}

// ---------------- q selection (chunked) ----------------
__global__ __launch_bounds__(64) void k_qsel(const float* __restrict__ y2,
    const float* __restrict__ w1, const float* __restrict__ b1,
    const int* __restrict__ argk, float* __restrict__ outq)
{
  __shared__ float yr[HH];
  __shared__ float part[64];
  int bj = blockIdx.x;
  int tid = threadIdx.x;
  const float4* row4 = (const float4*)&y2[(size_t)bj*HH];
  ((float4*)yr)[tid]    = row4[tid];
  ((float4*)yr)[tid+64] = row4[tid+64];
  __syncthreads();
  int k = argk[bj];
  int a = tid & 15, q4 = tid >> 4;
  const float* wp = &w1[(size_t)k*HH*AA + a];
  float s = 0.f;
  int h0 = q4*128;
  #pragma unroll 8
  for (int h=h0; h<h0+128; ++h) s += yr[h]*wp[(size_t)h*AA];
  part[tid] = s;
  __syncthreads();
  if (q4 == 0){
    float v = part[a] + part[a+16] + part[a+32] + part[a+48] + b1[k*AA + a];
    outq[(size_t)bj*AA + a] = v;
  }
}

// ---------------- orchestration ----------------
extern "C" void kernel_launch(void* const* d_in, const int* in_sizes, int n_in,
                              void* d_out, int out_size, void* d_ws, size_t ws_size,
                              hipStream_t stream)
{
  (void)in_sizes; (void)n_in; (void)out_size;
  const float* h1     = (const float*)d_in[0];
  const float* h2     = (const float*)d_in[1];
  const float* obs    = (const float*)d_in[2];
  const unsigned char* done_raw = (const unsigned char*)d_in[3];
  const float* W_embed=(const float*)d_in[4];  const float* b_embed=(const float*)d_in[5];
  const float* Wi1    =(const float*)d_in[6];  const float* bi1    =(const float*)d_in[7];
  const float* Wh1    =(const float*)d_in[8];  const float* bhn1   =(const float*)d_in[9];
  const float* W_sub  =(const float*)d_in[10]; const float* b_sub  =(const float*)d_in[11];
  const float* W_e1   =(const float*)d_in[12]; const float* b_e1   =(const float*)d_in[13];
  const float* W_e2   =(const float*)d_in[14]; const float* b_e2   =(const float*)d_in[15];
  const float* W_pol  =(const float*)d_in[16]; const float* b_pol  =(const float*)d_in[17];
  const float* Wi2    =(const float*)d_in[18]; const float* bi2    =(const float*)d_in[19];
  const float* Wh2    =(const float*)d_in[20]; const float* bhn2   =(const float*)d_in[21];
  const float* W_w1   =(const float*)d_in[22]; const float* b_w1   =(const float*)d_in[23];
  const float* W_b1   =(const float*)d_in[24]; const float* b_b1   =(const float*)d_in[25];

  float* out    = (float*)d_out;
  float* outHT1 = out;
  float* outHT2 = out + (size_t)NB*HH;
  float* outQ   = out + 2ull*NB*HH;
  float* outLG  = outQ + (size_t)TT*NB*AA;
  float* outSE  = outLG + (size_t)TT*BB*NN*KK;

  // ---- adaptive chunk size (float units) ----
  const size_t fixed_f = 2ull*NB*HH + (size_t)TT*NB + 1024
                       + (size_t)KK*HH*AA + 256 + (size_t)TT*NB + 64
                       + 2ull*DD*HH/2 * 2            // wembT, wpolT hi+lo pairs
                       + 4ull*H3*HH                  // wi1T,wi2T,wh1T,wh2T hi+lo pairs
                       + (size_t)HH*SS;              // wsubT hi+lo
  const size_t per_t_f = (size_t)NB*(2*HH + 2*H3 + SS)
                       + (size_t)NB*(HH/2 + DD + HH + HH);
  int CH = 64;
  while (CH > 1 && (fixed_f + per_t_f*(size_t)CH)*4 > ws_size) CH >>= 1;

  float* buf1   = (float*)d_ws;                        // y1 chunk: CH*NB*HH
  float* buf2   = buf1   + (size_t)CH*NB*HH;           // y2 chunk
  float* gbuf1  = buf2   + (size_t)CH*NB*HH;           // gi1 chunk
  float* gbuf2  = gbuf1  + (size_t)CH*NB*H3;           // gi2 chunk
  float* ae2buf = gbuf2  + (size_t)CH*NB*H3;           // CH*NB*SS
  float* h_last1= ae2buf + (size_t)CH*NB*SS;
  float* h_last2= h_last1+ (size_t)NB*HH;
  float* maskp  = h_last2+ (size_t)NB*HH;
  float* ws_e   = maskp  + (size_t)TT*NB;
  float* ws_w1  = ws_e   + 1024;
  float* ws_b1  = ws_w1  + (size_t)KK*HH*AA;
  int*   ws_argk= (int*)(ws_b1 + 256);
  int*   ws_flag= (int*)(ws_argk + (size_t)TT*NB);
  unsigned short* buf2bf = (unsigned short*)(ws_flag + 64);   // CH*NB*HH bf16 (sp)
  unsigned short* obs_h  = buf2bf + (size_t)CH*NB*HH;         // CH*NB*DD
  unsigned short* obs_l  = obs_h  + (size_t)CH*NB*DD;
  unsigned short* ae_h   = obs_l  + (size_t)CH*NB*DD;         // CH*NB*HH
  unsigned short* ae_l   = ae_h   + (size_t)CH*NB*HH;
  unsigned short* y1_h   = ae_l   + (size_t)CH*NB*HH;
  unsigned short* y1_l   = y1_h   + (size_t)CH*NB*HH;
  unsigned short* wembt_h= y1_l   + (size_t)CH*NB*HH;
  unsigned short* wembt_l= wembt_h+ (size_t)HH*DD;
  unsigned short* wpolt_h= wembt_l+ (size_t)HH*DD;
  unsigned short* wpolt_l= wpolt_h+ (size_t)HH*DD;
  unsigned short* wi1t_h = wpolt_l+ (size_t)HH*DD;
  unsigned short* wi1t_l = wi1t_h + (size_t)H3*HH;
  unsigned short* wi2t_h = wi1t_l + (size_t)H3*HH;
  unsigned short* wi2t_l = wi2t_h + (size_t)H3*HH;
  unsigned short* wh1t_h = wi2t_l + (size_t)H3*HH;
  unsigned short* wh1t_l = wh1t_h + (size_t)H3*HH;
  unsigned short* wh2t_h = wh1t_l + (size_t)H3*HH;
  unsigned short* wh2t_l = wh2t_h + (size_t)H3*HH;
  unsigned short* wsubt_h= wh2t_l + (size_t)H3*HH;
  unsigned short* wsubt_l= wsubt_h+ (size_t)SS*HH;

  // phase 0
  k_detect<<<1,256,0,stream>>>(done_raw, ws_flag);
  k_mask<<<TT*NB/256,256,0,stream>>>(done_raw, ws_flag, maskp);
  k_e<<<1,256,0,stream>>>(W_e1,b_e1,W_e2,b_e2,ws_e);
  k_w1b1<<<128,256,0,stream>>>(ws_e,W_w1,b_w1,W_b1,b_b1,ws_w1,ws_b1);
  k_se<<<2048,256,0,stream>>>(ws_e,outSE);
  k_tsplit<<<dim3(16,4),256,0,stream>>>(W_embed, wembt_h, wembt_l, DD, HH);
  k_tsplit<<<dim3(16,4),256,0,stream>>>(W_pol,   wpolt_h, wpolt_l, DD, HH);
  k_tsplit<<<dim3(48,16),256,0,stream>>>(Wi1, wi1t_h, wi1t_l, HH, H3);
  k_tsplit<<<dim3(48,16),256,0,stream>>>(Wi2, wi2t_h, wi2t_l, HH, H3);
  k_tsplit<<<dim3(48,16),256,0,stream>>>(Wh1, wh1t_h, wh1t_l, HH, H3);
  k_tsplit<<<dim3(48,16),256,0,stream>>>(Wh2, wh2t_h, wh2t_l, HH, H3);
  k_tsplit<<<dim3(2,16),256,0,stream>>>(W_sub, wsubt_h, wsubt_l, HH, SS);
  k_copy<<<512,256,0,stream>>>(h1, h_last1, NB*HH/4);
  k_copy<<<512,256,0,stream>>>(h2, h_last2, NB*HH/4);

  dim3 thr(256);
  const int NCH = TT / CH;
  for (int c = 0; c < NCH; ++c){
    int t0 = c * CH;
    int M = CH*NB;
    const float* obs_c = obs + (size_t)t0*NB*DD;
    k_split_cast<<<(M*DD/8+255)/256,256,0,stream>>>(obs_c, obs_h, obs_l, M*DD/8);
    mfma_gemm<DD,1,128,1,2><<<dim3(HH/128, M/128),thr,0,stream>>>(
        obs_h, obs_l, wembt_h, wembt_l, b_embed, nullptr, ae_h, ae_l, HH);
    mfma_gemm<HH,1,128,0,0><<<dim3(H3/128, M/128),thr,0,stream>>>(
        ae_h, ae_l, wi1t_h, wi1t_l, bi1, gbuf1, nullptr, nullptr, H3);
    mfma_gemm<DD,0,128,1,1><<<dim3(HH/128, M/128),thr,0,stream>>>(
        obs_h, obs_h, wpolt_h, wpolt_h, b_pol, nullptr, buf2bf, nullptr, HH);
    mfma_gemm<HH,0,128,0,0><<<dim3(H3/128, M/128),thr,0,stream>>>(
        buf2bf, buf2bf, wi2t_h, wi2t_h, bi2, gbuf2, nullptr, nullptr, H3);
    // dual-GRU scan: 32x32 MFMA + reg-prefetch; GRU1 epilogue emits y1 hi/lo
    for (int lt = 0; lt < CH; ++lt){
      const float* hp1 = (lt == 0) ? h_last1 : (buf1 + (size_t)(lt-1)*NB*HH);
      const float* hp2 = (lt == 0) ? h_last2 : (buf2 + (size_t)(lt-1)*NB*HH);
      gru_step_mix3<<<256, 256, 0, stream>>>(hp1, hp2,
                                             gbuf1 + (size_t)lt*NB*H3, gbuf2 + (size_t)lt*NB*H3,
                                             wh1t_h, wh1t_l, wh2t_h, bhn1, bhn2,
                                             maskp + (size_t)(t0+lt)*NB,
                                             buf1 + (size_t)lt*NB*HH, buf2 + (size_t)lt*NB*HH,
                                             y1_h + (size_t)lt*NB*HH, y1_l + (size_t)lt*NB*HH);
    }
    k_copy<<<512,256,0,stream>>>(buf1 + (size_t)(CH-1)*NB*HH, h_last1, NB*HH/4);
    k_copy<<<512,256,0,stream>>>(buf2 + (size_t)(CH-1)*NB*HH, h_last2, NB*HH/4);
    // tails: ae2 via split MFMA (y1 pair already written by the scan), logits, qsel
    mfma_gemm<HH,1,64,0,0><<<dim3(1, M/128),thr,0,stream>>>(
        y1_h, y1_l, wsubt_h, wsubt_l, b_sub, ae2buf, nullptr, nullptr, SS);
    k_logits<<<M/256,256,0,stream>>>(ae2buf, ws_e, outLG, ws_argk, t0);
    k_qsel<<<M,64,0,stream>>>(buf2, ws_w1, ws_b1, ws_argk + (size_t)t0*NB, outQ + (size_t)t0*NB*AA);
  }
  k_copy<<<512,256,0,stream>>>(h_last1, outHT1, NB*HH/4);
  k_copy<<<512,256,0,stream>>>(h_last2, outHT2, NB*HH/4);
}